// Round 1
// baseline (527.362 us; speedup 1.0000x reference)
//
#include <hip/hip_runtime.h>
#include <hip/hip_bf16.h>

// Problem constants: latent (16,192,64,64) fp32, codebook (1024,192) fp32.
// N = 16*64*64 = 65536 points, D = 192, K = 1024.
// d_out = [quantized: 12582912 fp32][indices-as-float: 65536] = 12648448 el.

#define NPTS   65536
#define DIMS   192
#define KCB    1024
#define HW     4096
#define QELEMS 12582912

#define TM   128   // points per block (k_dist)
#define TK   128   // codewords per k-tile
#define DCH  64    // d-chunk staged in LDS
#define LDX  132   // padded LDS row stride (breaks bank conflicts; 132%32=4)

// ---------------- kernel 1: per-point inverse norms ----------------
// block = 256 thr handles 128 consecutive points (within one b: 128 | 4096).
__global__ __launch_bounds__(256) void k_norms(const float* __restrict__ latent,
                                               float* __restrict__ inv_norm) {
    __shared__ float red[256];
    const int tid = threadIdx.x;
    const int n0 = blockIdx.x * 128;
    const int nl = tid & 127;
    const int half = tid >> 7;          // 0/1 — channel interleave
    const int b = n0 >> 12;
    const int hw = (n0 & 4095) + nl;
    const float* base = latent + (size_t)b * DIMS * HW + hw;
    float ssq = 0.f;
    for (int c = half; c < DIMS; c += 2) {
        float v = base[(size_t)c * HW];   // 128 consecutive lanes -> coalesced
        ssq = fmaf(v, v, ssq);
    }
    red[tid] = ssq;
    __syncthreads();
    if (half == 0) {
        float s = red[tid] + red[tid + 128];
        inv_norm[n0 + nl] = 1.0f / (sqrtf(s) + 1e-8f);
    }
}

// ---------------- kernel 1b: codebook row squared norms ----------------
__global__ __launch_bounds__(256) void k_c2(const float* __restrict__ cbk,
                                            float* __restrict__ c2) {
    int k = blockIdx.x * 256 + threadIdx.x;
    if (k >= KCB) return;
    const float4* row = (const float4*)(cbk + (size_t)k * DIMS);
    float s = 0.f;
    #pragma unroll
    for (int i = 0; i < DIMS / 4; ++i) {
        float4 v = row[i];
        s += v.x * v.x + v.y * v.y + v.z * v.z + v.w * v.w;
    }
    c2[k] = s;
}

// ---------------- kernel 2: fused distance GEMM + argmin ----------------
// grid 512 blocks (128 pts each) x 256 thr; thread micro-tile 8 pts x 8 cw.
__global__ __launch_bounds__(256) void k_dist(const float* __restrict__ latent,
                                              const float* __restrict__ cbk,
                                              const float* __restrict__ inv_norm,
                                              const float* __restrict__ c2,
                                              int* __restrict__ idx_out,
                                              float* __restrict__ idxf_out) {
    __shared__ __align__(16) float xs[DCH * LDX];   // xs[d][n], padded
    __shared__ __align__(16) float cs[DCH * LDX];   // cs[d][k], padded
    __shared__ unsigned long long red[TM];

    const int tid = threadIdx.x;
    const int n0 = blockIdx.x * TM;
    const int b = n0 >> 12;
    const int hw0 = n0 & 4095;
    const int kt = tid & 15;    // codeword-group index (16)
    const int mt = tid >> 4;    // point-group index (16)

    const float* lat_base = latent + (size_t)b * DIMS * HW + hw0;

    float inv[8];
    #pragma unroll
    for (int i = 0; i < 8; ++i) inv[i] = inv_norm[n0 + mt * 8 + i];

    float best[8];
    int bidx[8];
    #pragma unroll
    for (int i = 0; i < 8; ++i) { best[i] = 3.4e38f; bidx[i] = 0; }

    const int nl = tid & 127;   // x-staging lane
    const int cp = tid >> 7;    // x-staging channel phase (0/1)

    for (int k0 = 0; k0 < KCB; k0 += TK) {
        float acc[8][8];
        #pragma unroll
        for (int i = 0; i < 8; ++i)
            #pragma unroll
            for (int j = 0; j < 8; ++j) acc[i][j] = 0.f;

        for (int d0 = 0; d0 < DIMS; d0 += DCH) {
            __syncthreads();
            // stage x chunk: 64 channels x 128 points, coalesced along n
            for (int cc = cp; cc < DCH; cc += 2) {
                xs[cc * LDX + nl] = lat_base[(size_t)(d0 + cc) * HW + nl];
            }
            // stage codebook chunk transposed: 128 cw x 64 d = 2048 float4
            #pragma unroll
            for (int i = 0; i < 8; ++i) {
                int f4 = tid + 256 * i;
                int kk = f4 >> 4;          // codeword within tile
                int dq = f4 & 15;          // float4 index within chunk
                float4 v = *(const float4*)(cbk + (size_t)(k0 + kk) * DIMS + d0 + dq * 4);
                cs[(dq * 4 + 0) * LDX + kk] = v.x;
                cs[(dq * 4 + 1) * LDX + kk] = v.y;
                cs[(dq * 4 + 2) * LDX + kk] = v.z;
                cs[(dq * 4 + 3) * LDX + kk] = v.w;
            }
            __syncthreads();
            // compute: 64 FMAs per d-step per thread, 4x ds_read_b128
            for (int d = 0; d < DCH; ++d) {
                const float* xr = &xs[d * LDX + mt * 8];
                const float* cr = &cs[d * LDX + kt * 8];
                float x8[8], c8[8];
                *(float4*)&x8[0] = *(const float4*)&xr[0];
                *(float4*)&x8[4] = *(const float4*)&xr[4];
                *(float4*)&c8[0] = *(const float4*)&cr[0];
                *(float4*)&c8[4] = *(const float4*)&cr[4];
                #pragma unroll
                for (int i = 0; i < 8; ++i)
                    #pragma unroll
                    for (int j = 0; j < 8; ++j)
                        acc[i][j] = fmaf(x8[i], c8[j], acc[i][j]);
            }
        }
        // epilogue: dist = c2[k] - 2*inv*dot ; argmin-equivalent to reference
        float cc2[8];
        #pragma unroll
        for (int j = 0; j < 8; ++j) cc2[j] = c2[k0 + kt * 8 + j];
        #pragma unroll
        for (int i = 0; i < 8; ++i) {
            #pragma unroll
            for (int j = 0; j < 8; ++j) {
                float t = inv[i] * acc[i][j];
                float dist = fmaf(-2.f, t, cc2[j]);
                int kidx = k0 + kt * 8 + j;
                if (dist < best[i]) { best[i] = dist; bidx[i] = kidx; }
            }
        }
    }

    // cross-thread argmin reduce: packed (dist_bits<<32)|k, min = lowest dist
    // then lowest k (matches jnp.argmin first-occurrence tie-break).
    if (tid < TM) red[tid] = ~0ull;
    __syncthreads();
    #pragma unroll
    for (int i = 0; i < 8; ++i) {
        unsigned long long p =
            ((unsigned long long)__float_as_uint(best[i]) << 32) | (unsigned)bidx[i];
        atomicMin(&red[mt * 8 + i], p);
    }
    __syncthreads();
    if (tid < TM) {
        int k = (int)(red[tid] & 0xFFFFFFFFu);
        idx_out[n0 + tid] = k;
        idxf_out[n0 + tid] = (float)k;
    }
}

// ---------------- kernel 3: gather + transpose to [B,C,H,W] ----------------
// block = 256 thr handles 64 points; LDS-staged for coalesced writes.
__global__ __launch_bounds__(256) void k_gather(const float* __restrict__ cbk,
                                                const int* __restrict__ idx,
                                                float* __restrict__ out) {
    __shared__ float q[64 * 193];   // q[n][c], 193%32==1 -> conflict-free
    __shared__ int sidx[64];
    const int tid = threadIdx.x;
    const int n0 = blockIdx.x * 64;
    const int b = n0 >> 12;
    const int hw0 = n0 & 4095;
    const int lane = tid & 63;
    const int grp = tid >> 6;   // 0..3

    if (tid < 64) sidx[tid] = idx[n0 + tid];
    __syncthreads();

    for (int r = grp; r < 64; r += 4) {
        const float* row = cbk + (size_t)sidx[r] * DIMS;
        for (int c = lane; c < DIMS; c += 64) q[r * 193 + c] = row[c];
    }
    __syncthreads();

    float* obase = out + (size_t)b * DIMS * HW + hw0;
    for (int c = grp; c < DIMS; c += 4) {
        obase[(size_t)c * HW + lane] = q[lane * 193 + c];   // 256B coalesced
    }
}

extern "C" void kernel_launch(void* const* d_in, const int* in_sizes, int n_in,
                              void* d_out, int out_size, void* d_ws, size_t ws_size,
                              hipStream_t stream) {
    const float* latent = (const float*)d_in[0];
    const float* cbk = (const float*)d_in[1];
    float* out = (float*)d_out;

    // workspace layout: inv_norm[N] | c2[K] | idx[N] (~528 KB)
    float* inv_norm = (float*)d_ws;
    float* c2 = inv_norm + NPTS;
    int* idx = (int*)(c2 + KCB);

    float* out_q = out;              // quantized [B,C,H,W]
    float* out_idx = out + QELEMS;   // indices as float [B,H,W]

    k_norms<<<NPTS / 128, 256, 0, stream>>>(latent, inv_norm);
    k_c2<<<(KCB + 255) / 256, 256, 0, stream>>>(cbk, c2);
    k_dist<<<NPTS / TM, 256, 0, stream>>>(latent, cbk, inv_norm, c2, idx, out_idx);
    k_gather<<<NPTS / 64, 256, 0, stream>>>(cbk, idx, out_q);
}

// Round 2
// 410.534 us; speedup vs baseline: 1.2846x; 1.2846x over previous
//
#include <hip/hip_runtime.h>
#include <hip/hip_bf16.h>

// Problem: latent (16,192,64,64) fp32, codebook (1024,192) fp32.
// N = 65536 points, D = 192, K = 1024.
// d_out = [quantized: 12582912 fp32][indices-as-float: 65536].

#define NPTS   65536
#define DIMS   192
#define KCB    1024
#define HW     4096
#define QELEMS 12582912

typedef __attribute__((ext_vector_type(8))) short bf16x8;
typedef __attribute__((ext_vector_type(4))) float f32x4;

// ============================ MFMA path =================================
// A' = normalized-x split: [n][48 units16B] = [hi(24)|lo(24)] bf16
// B' = codebook split:     [k][48 units16B] = [hi(24)|lo(24)] bf16
// GEMM K'=576: dc 0-2 (A hi,B hi), dc 3-5 (A hi,B lo), dc 6-8 (A lo,B hi)
//   => dot ~ xh*ch + xh*cl + xl*ch  (error ~2e-5 worst, ~2e-6 typ)

#define MARGIN_Q 384u   // 3.7e-4 in quant units (2^-20 * dist+1 scale)

__device__ __forceinline__ void async_load16(const void* g, void* l) {
    __builtin_amdgcn_global_load_lds(
        (const __attribute__((address_space(1))) unsigned int*)g,
        (__attribute__((address_space(3))) unsigned int*)l, 16, 0, 0);
}

__device__ __forceinline__ unsigned qdist(float d) {
    float t = (d + 1.0f) * 1048576.0f;          // dist in [-1,3] -> [0,2^22)
    t = fminf(fmaxf(t, 0.0f), 4194303.0f);
    return (unsigned)t;
}

__device__ __forceinline__ void top2_merge(unsigned& b, unsigned& s,
                                           unsigned ob, unsigned os) {
    unsigned nb = min(b, ob);
    unsigned ns = min(max(b, ob), min(s, os));
    b = nb; s = ns;
}

// ---- split latent -> normalized bf16 hi/lo, layout [n][384] ----
__global__ __launch_bounds__(256) void k_split(const float* __restrict__ latent,
                                               ushort* __restrict__ Ap) {
    __shared__ float xs[64 * 193];
    __shared__ float part[4 * 64];
    __shared__ float invs[64];
    const int tid = threadIdx.x;
    const int n0 = blockIdx.x * 64;
    const int b = n0 >> 12;
    const int hw0 = n0 & 4095;
    const int p = tid & 63;
    const int ph = tid >> 6;

    const float* base = latent + (size_t)b * DIMS * HW + hw0 + p;
    float ssq = 0.f;
    for (int i = 0; i < 48; ++i) {
        int cc = ph + i * 4;
        float v = base[(size_t)cc * HW];      // 64 lanes coalesced
        xs[p * 193 + cc] = v;
        ssq = fmaf(v, v, ssq);
    }
    part[ph * 64 + p] = ssq;
    __syncthreads();
    if (tid < 64) {
        float s = part[tid] + part[64 + tid] + part[128 + tid] + part[192 + tid];
        invs[tid] = 1.0f / (sqrtf(s) + 1e-8f);
    }
    __syncthreads();

    // write 3072 16B-units: u -> (p, ch); ch<24: hi, else lo
    uint4* out = (uint4*)Ap;
    for (int i = 0; i < 12; ++i) {
        int u = i * 256 + tid;
        int pp = u / 48;
        int ch = u % 48;
        int dd = (ch % 24) * 8;
        bool hi_region = ch < 24;
        float inv = invs[pp];
        unsigned w[4];
        #pragma unroll
        for (int j = 0; j < 4; ++j) {
            unsigned short h2[2];
            #pragma unroll
            for (int e = 0; e < 2; ++e) {
                float f = xs[pp * 193 + dd + j * 2 + e] * inv;
                __hip_bfloat16 h = __float2bfloat16(f);
                if (!hi_region) {
                    float r = f - __bfloat162float(h);
                    h = __float2bfloat16(r);
                }
                h2[e] = *(unsigned short*)&h;
            }
            w[j] = (unsigned)h2[0] | ((unsigned)h2[1] << 16);
        }
        out[(size_t)(n0) * 48 + u] = make_uint4(w[0], w[1], w[2], w[3]);
    }
}

// ---- split codebook -> bf16 hi/lo, layout [k][384] ----
__global__ __launch_bounds__(256) void k_prep_cb(const float* __restrict__ cbk,
                                                 ushort* __restrict__ Bp) {
    int u = blockIdx.x * 256 + threadIdx.x;     // 49152 units
    if (u >= KCB * 48) return;
    int k = u / 48;
    int ch = u % 48;
    int dd = (ch % 24) * 8;
    bool hi_region = ch < 24;
    const float* row = cbk + (size_t)k * DIMS + dd;
    unsigned w[4];
    #pragma unroll
    for (int j = 0; j < 4; ++j) {
        unsigned short h2[2];
        #pragma unroll
        for (int e = 0; e < 2; ++e) {
            float f = row[j * 2 + e];
            __hip_bfloat16 h = __float2bfloat16(f);
            if (!hi_region) {
                float r = f - __bfloat162float(h);
                h = __float2bfloat16(r);
            }
            h2[e] = *(unsigned short*)&h;
        }
        w[j] = (unsigned)h2[0] | ((unsigned)h2[1] << 16);
    }
    ((uint4*)Bp)[u] = make_uint4(w[0], w[1], w[2], w[3]);
}

// ---- codebook row squared norms ----
__global__ __launch_bounds__(256) void k_c2(const float* __restrict__ cbk,
                                            float* __restrict__ c2) {
    int k = blockIdx.x * 256 + threadIdx.x;
    if (k >= KCB) return;
    const float4* row = (const float4*)(cbk + (size_t)k * DIMS);
    float s = 0.f;
    #pragma unroll
    for (int i = 0; i < DIMS / 4; ++i) {
        float4 v = row[i];
        s += v.x * v.x + v.y * v.y + v.z * v.z + v.w * v.w;
    }
    c2[k] = s;
}

// ---- MFMA distance GEMM + per-(point, nb) top-2 ----
// grid 4096 = 512 mblk (low bits) x 8 nb (high bits); 256 thr = 4 waves,
// wave tile 64x64 (4x4 of 16x16x32 bf16). LDS 128x64 bf16 per operand,
// XOR-swizzled 16B chunks (2-way bank conflicts only).
__global__ __launch_bounds__(256, 3) void k_gemm(const ushort* __restrict__ Ap,
                                                 const ushort* __restrict__ Bp,
                                                 const float* __restrict__ c2,
                                                 uint2* __restrict__ best2) {
    __shared__ __align__(16) ushort As[128 * 64];
    __shared__ __align__(16) ushort Bs[128 * 64];
    __shared__ uint2 t2buf[128 * 2];

    const int tid = threadIdx.x;
    const int wave = tid >> 6;
    const int lane = tid & 63;
    const int quad = lane >> 4;
    const int l15 = lane & 15;
    const int mblk = blockIdx.x & 511;
    const int nb = blockIdx.x >> 9;
    const int wm = (wave >> 1) * 64;
    const int wn = (wave & 1) * 64;

    f32x4 acc[4][4];
    #pragma unroll
    for (int mt = 0; mt < 4; ++mt)
        #pragma unroll
        for (int nt = 0; nt < 4; ++nt)
            #pragma unroll
            for (int r = 0; r < 4; ++r) acc[mt][nt][r] = 0.f;

    const size_t arow0 = (size_t)mblk * 128;
    const size_t brow0 = (size_t)nb * 128;

    for (int dc = 0; dc < 9; ++dc) {
        // region select: A: dc0-5 -> hi (units 0..23), dc6-8 -> lo (24..47)
        //                B: dc0-2 hi, dc3-5 -> lo, dc6-8 -> hi
        int ga = (dc < 3 ? dc : dc - 3) * 8;
        int gb = (dc < 6 ? dc : dc - 6) * 8;
        __syncthreads();
        #pragma unroll
        for (int i = 0; i < 4; ++i) {
            int u = i * 256 + tid;            // 0..1023 16B-units
            int m = u >> 3;
            int c = u & 7;
            int sw = c ^ (m & 7);
            async_load16(Ap + ((arow0 + m) * 48 + ga + sw) * 8, &As[u * 8]);
            async_load16(Bp + ((brow0 + m) * 48 + gb + sw) * 8, &Bs[u * 8]);
        }
        __syncthreads();
        #pragma unroll
        for (int s = 0; s < 2; ++s) {
            bf16x8 af[4], bfr[4];
            #pragma unroll
            for (int mt = 0; mt < 4; ++mt) {
                int m = wm + mt * 16 + l15;
                int c = (s * 4 + quad) ^ (m & 7);
                af[mt] = *(const bf16x8*)&As[m * 64 + c * 8];
            }
            #pragma unroll
            for (int nt = 0; nt < 4; ++nt) {
                int n = wn + nt * 16 + l15;
                int c = (s * 4 + quad) ^ (n & 7);
                bfr[nt] = *(const bf16x8*)&Bs[n * 64 + c * 8];
            }
            #pragma unroll
            for (int mt = 0; mt < 4; ++mt)
                #pragma unroll
                for (int nt = 0; nt < 4; ++nt)
                    acc[mt][nt] = __builtin_amdgcn_mfma_f32_16x16x32_bf16(
                        af[mt], bfr[nt], acc[mt][nt], 0, 0, 0);
        }
    }

    // epilogue: dist = c2[k] - 2*dot (x normalized); top-2 packed (q<<10)|k
    int kcol[4];
    float cc2[4];
    #pragma unroll
    for (int nt = 0; nt < 4; ++nt) {
        kcol[nt] = nb * 128 + wn + nt * 16 + l15;
        cc2[nt] = c2[kcol[nt]];
    }
    #pragma unroll
    for (int mt = 0; mt < 4; ++mt) {
        #pragma unroll
        for (int r = 0; r < 4; ++r) {
            unsigned p[4];
            #pragma unroll
            for (int nt = 0; nt < 4; ++nt) {
                float dist = fmaf(-2.f, acc[mt][nt][r], cc2[nt]);
                p[nt] = (qdist(dist) << 10) | (unsigned)kcol[nt];
            }
            unsigned b01 = min(p[0], p[1]), s01 = max(p[0], p[1]);
            unsigned b23 = min(p[2], p[3]), s23 = max(p[2], p[3]);
            unsigned b = min(b01, b23);
            unsigned s = min(max(b01, b23), min(s01, s23));
            #pragma unroll
            for (int off = 1; off < 16; off <<= 1) {
                unsigned ob = __shfl_xor(b, off, 64);
                unsigned os = __shfl_xor(s, off, 64);
                top2_merge(b, s, ob, os);
            }
            if (l15 == 0) {
                int mloc = wm + mt * 16 + quad * 4 + r;
                t2buf[mloc * 2 + (wave & 1)] = make_uint2(b, s);
            }
        }
    }
    __syncthreads();
    if (tid < 128) {
        uint2 x = t2buf[tid * 2];
        uint2 y = t2buf[tid * 2 + 1];
        unsigned b = x.x, s = x.y;
        top2_merge(b, s, y.x, y.y);
        best2[(arow0 + tid) * 8 + nb] = make_uint2(b, s);
    }
}

// ---- merge 8 nb-partials -> argmin; flag narrow-gap points ----
__global__ __launch_bounds__(256) void k_combine(const uint2* __restrict__ best2,
                                                 int* __restrict__ idx,
                                                 float* __restrict__ idxf,
                                                 int* __restrict__ list,
                                                 int* __restrict__ cnt) {
    int n = blockIdx.x * 256 + threadIdx.x;
    unsigned b = 0xFFFFFFFFu, s = 0xFFFFFFFFu;
    #pragma unroll
    for (int j = 0; j < 8; ++j) {
        uint2 v = best2[(size_t)n * 8 + j];
        top2_merge(b, s, v.x, v.y);
    }
    int k = (int)(b & 1023u);
    idx[n] = k;
    idxf[n] = (float)k;
    if (((s >> 10) - (b >> 10)) < MARGIN_Q) {
        int pos = atomicAdd(cnt, 1);
        list[pos] = n;
    }
}

// ---- exact fp32 rescore of flagged points ----
__global__ __launch_bounds__(256) void k_rescore(const float* __restrict__ latent,
                                                 const float* __restrict__ cbk,
                                                 const float* __restrict__ c2,
                                                 const int* __restrict__ list,
                                                 const int* __restrict__ cnt,
                                                 int* __restrict__ idx,
                                                 float* __restrict__ idxf) {
    __shared__ float xs[DIMS];
    __shared__ float sinv;
    __shared__ unsigned long long best;
    const int tid = threadIdx.x;
    const int count = *cnt;
    for (int fi = blockIdx.x; fi < count; fi += gridDim.x) {
        int n = list[fi];
        int b = n >> 12, hw = n & 4095;
        __syncthreads();
        if (tid < DIMS) xs[tid] = latent[((size_t)b * DIMS + tid) * HW + hw];
        if (tid == 0) best = ~0ull;
        __syncthreads();
        if (tid == 0) {
            float ss = 0.f;
            for (int d = 0; d < DIMS; ++d) ss = fmaf(xs[d], xs[d], ss);
            sinv = 1.0f / (sqrtf(ss) + 1e-8f);
        }
        __syncthreads();
        float inv = sinv;
        unsigned long long loc = ~0ull;
        #pragma unroll
        for (int j = 0; j < 4; ++j) {
            int k = j * 256 + tid;
            const float4* row = (const float4*)(cbk + (size_t)k * DIMS);
            float dot = 0.f;
            #pragma unroll
            for (int i = 0; i < DIMS / 4; ++i) {
                float4 cv = row[i];
                const float4 xv = *(const float4*)&xs[i * 4];
                dot = fmaf(xv.x, cv.x, dot);
                dot = fmaf(xv.y, cv.y, dot);
                dot = fmaf(xv.z, cv.z, dot);
                dot = fmaf(xv.w, cv.w, dot);
            }
            float dist = c2[k] - 2.f * inv * dot;
            unsigned ub = __float_as_uint(dist);
            ub ^= (ub >> 31) ? 0xFFFFFFFFu : 0x80000000u;   // monotonic map
            unsigned long long pk = ((unsigned long long)ub << 32) | (unsigned)k;
            loc = loc < pk ? loc : pk;
        }
        atomicMin(&best, loc);
        __syncthreads();
        if (tid == 0) {
            int k = (int)(best & 0xFFFFFFFFull);
            idx[n] = k;
            idxf[n] = (float)k;
        }
    }
}

// ---- gather + transpose to [B,C,H,W] ----
__global__ __launch_bounds__(256) void k_gather(const float* __restrict__ cbk,
                                                const int* __restrict__ idx,
                                                float* __restrict__ out) {
    __shared__ float q[64 * 193];
    __shared__ int sidx[64];
    const int tid = threadIdx.x;
    const int n0 = blockIdx.x * 64;
    const int b = n0 >> 12;
    const int hw0 = n0 & 4095;
    const int lane = tid & 63;
    const int grp = tid >> 6;

    if (tid < 64) sidx[tid] = idx[n0 + tid];
    __syncthreads();
    for (int r = grp; r < 64; r += 4) {
        const float* row = cbk + (size_t)sidx[r] * DIMS;
        for (int c = lane; c < DIMS; c += 64) q[r * 193 + c] = row[c];
    }
    __syncthreads();
    float* obase = out + (size_t)b * DIMS * HW + hw0;
    for (int c = grp; c < DIMS; c += 4) {
        obase[(size_t)c * HW + lane] = q[lane * 193 + c];
    }
}

// ======================= fallback fp32 path (round-1) ====================
__global__ __launch_bounds__(256) void k_norms_fb(const float* __restrict__ latent,
                                                  float* __restrict__ inv_norm) {
    __shared__ float red[256];
    const int tid = threadIdx.x;
    const int n0 = blockIdx.x * 128;
    const int nl = tid & 127;
    const int half = tid >> 7;
    const int b = n0 >> 12;
    const int hw = (n0 & 4095) + nl;
    const float* base = latent + (size_t)b * DIMS * HW + hw;
    float ssq = 0.f;
    for (int c = half; c < DIMS; c += 2) {
        float v = base[(size_t)c * HW];
        ssq = fmaf(v, v, ssq);
    }
    red[tid] = ssq;
    __syncthreads();
    if (half == 0) {
        float s = red[tid] + red[tid + 128];
        inv_norm[n0 + nl] = 1.0f / (sqrtf(s) + 1e-8f);
    }
}

#define LDX  132
__global__ __launch_bounds__(256) void k_dist_fb(const float* __restrict__ latent,
                                                 const float* __restrict__ cbk,
                                                 const float* __restrict__ inv_norm,
                                                 const float* __restrict__ c2,
                                                 int* __restrict__ idx_out,
                                                 float* __restrict__ idxf_out) {
    __shared__ __align__(16) float xsm[64 * LDX];
    __shared__ __align__(16) float csm[64 * LDX];
    __shared__ unsigned long long red[128];
    const int tid = threadIdx.x;
    const int n0 = blockIdx.x * 128;
    const int b = n0 >> 12;
    const int hw0 = n0 & 4095;
    const int kt = tid & 15;
    const int mt = tid >> 4;
    const float* lat_base = latent + (size_t)b * DIMS * HW + hw0;
    float inv[8];
    #pragma unroll
    for (int i = 0; i < 8; ++i) inv[i] = inv_norm[n0 + mt * 8 + i];
    float best[8];
    int bidx[8];
    #pragma unroll
    for (int i = 0; i < 8; ++i) { best[i] = 3.4e38f; bidx[i] = 0; }
    const int nl = tid & 127;
    const int cp = tid >> 7;
    for (int k0 = 0; k0 < KCB; k0 += 128) {
        float acc[8][8];
        #pragma unroll
        for (int i = 0; i < 8; ++i)
            #pragma unroll
            for (int j = 0; j < 8; ++j) acc[i][j] = 0.f;
        for (int d0 = 0; d0 < DIMS; d0 += 64) {
            __syncthreads();
            for (int cc = cp; cc < 64; cc += 2)
                xsm[cc * LDX + nl] = lat_base[(size_t)(d0 + cc) * HW + nl];
            #pragma unroll
            for (int i = 0; i < 8; ++i) {
                int f4 = tid + 256 * i;
                int kk = f4 >> 4;
                int dq = f4 & 15;
                float4 v = *(const float4*)(cbk + (size_t)(k0 + kk) * DIMS + d0 + dq * 4);
                csm[(dq * 4 + 0) * LDX + kk] = v.x;
                csm[(dq * 4 + 1) * LDX + kk] = v.y;
                csm[(dq * 4 + 2) * LDX + kk] = v.z;
                csm[(dq * 4 + 3) * LDX + kk] = v.w;
            }
            __syncthreads();
            for (int d = 0; d < 64; ++d) {
                const float* xr = &xsm[d * LDX + mt * 8];
                const float* cr = &csm[d * LDX + kt * 8];
                float x8[8], c8[8];
                *(float4*)&x8[0] = *(const float4*)&xr[0];
                *(float4*)&x8[4] = *(const float4*)&xr[4];
                *(float4*)&c8[0] = *(const float4*)&cr[0];
                *(float4*)&c8[4] = *(const float4*)&cr[4];
                #pragma unroll
                for (int i = 0; i < 8; ++i)
                    #pragma unroll
                    for (int j = 0; j < 8; ++j)
                        acc[i][j] = fmaf(x8[i], c8[j], acc[i][j]);
            }
        }
        float cc2[8];
        #pragma unroll
        for (int j = 0; j < 8; ++j) cc2[j] = c2[k0 + kt * 8 + j];
        #pragma unroll
        for (int i = 0; i < 8; ++i)
            #pragma unroll
            for (int j = 0; j < 8; ++j) {
                float t = inv[i] * acc[i][j];
                float dist = fmaf(-2.f, t, cc2[j]);
                int kidx = k0 + kt * 8 + j;
                if (dist < best[i]) { best[i] = dist; bidx[i] = kidx; }
            }
    }
    if (tid < 128) red[tid] = ~0ull;
    __syncthreads();
    #pragma unroll
    for (int i = 0; i < 8; ++i) {
        unsigned long long p =
            ((unsigned long long)__float_as_uint(best[i]) << 32) | (unsigned)bidx[i];
        atomicMin(&red[mt * 8 + i], p);
    }
    __syncthreads();
    if (tid < 128) {
        int k = (int)(red[tid] & 0xFFFFFFFFu);
        idx_out[n0 + tid] = k;
        idxf_out[n0 + tid] = (float)k;
    }
}

// ================================ launch ================================
extern "C" void kernel_launch(void* const* d_in, const int* in_sizes, int n_in,
                              void* d_out, int out_size, void* d_ws, size_t ws_size,
                              hipStream_t stream) {
    const float* latent = (const float*)d_in[0];
    const float* cbk = (const float*)d_in[1];
    float* out = (float*)d_out;
    float* out_q = out;
    float* out_idx = out + QELEMS;

    if (ws_size >= 56u * 1024u * 1024u) {
        // ws layout (bytes):
        char* w = (char*)d_ws;
        ushort* Ap = (ushort*)w;                               // 50,331,648
        ushort* Bp = (ushort*)(w + 50331648);                  //    786,432
        float* c2 = (float*)(w + 51118080);                    //      4,096
        uint2* best2 = (uint2*)(w + 51122176);                 //  4,194,304
        int* idx = (int*)(w + 55316480);                       //    262,144
        int* list = (int*)(w + 55578624);                      //    262,144
        int* cnt = (int*)(w + 55840768);                       //          4

        hipMemsetAsync(cnt, 0, 4, stream);
        k_split<<<NPTS / 64, 256, 0, stream>>>(latent, Ap);
        k_prep_cb<<<192, 256, 0, stream>>>(cbk, Bp);
        k_c2<<<4, 256, 0, stream>>>(cbk, c2);
        k_gemm<<<4096, 256, 0, stream>>>(Ap, Bp, c2, best2);
        k_combine<<<256, 256, 0, stream>>>(best2, idx, out_idx, list, cnt);
        k_rescore<<<240, 256, 0, stream>>>(latent, cbk, c2, list, cnt, idx, out_idx);
        k_gather<<<NPTS / 64, 256, 0, stream>>>(cbk, idx, out_q);
    } else {
        float* inv_norm = (float*)d_ws;
        float* c2 = inv_norm + NPTS;
        int* idx = (int*)(c2 + KCB);
        k_norms_fb<<<NPTS / 128, 256, 0, stream>>>(latent, inv_norm);
        k_c2<<<4, 256, 0, stream>>>(cbk, c2);
        k_dist_fb<<<NPTS / 128, 256, 0, stream>>>(latent, cbk, inv_norm, c2, idx, out_idx);
        k_gather<<<NPTS / 64, 256, 0, stream>>>(cbk, idx, out_q);
    }
}

// Round 3
// 289.229 us; speedup vs baseline: 1.8233x; 1.4194x over previous
//
#include <hip/hip_runtime.h>
#include <hip/hip_bf16.h>

// Problem: latent (16,192,64,64) fp32, codebook (1024,192) fp32.
// N = 65536 points, D = 192, K = 1024.
// d_out = [quantized: 12582912 fp32][indices-as-float: 65536].

#define NPTS   65536
#define DIMS   192
#define KCB    1024
#define HW     4096
#define QELEMS 12582912

typedef __attribute__((ext_vector_type(8))) short bf16x8;
typedef __attribute__((ext_vector_type(4))) float f32x4;

// ============================ MFMA path =================================
// A' = normalized-x split: [n][48 units16B] = [hi(24)|lo(24)] bf16
// B' = codebook split:     [k][48 units16B] = [hi(24)|lo(24)] bf16
// GEMM K'=576: dc 0-2 (A hi,B hi), dc 3-5 (A hi,B lo), dc 6-8 (A lo,B hi)
//   => dot ~ xh*ch + xh*cl + xl*ch
// Worst-case dist error (Cauchy-Schwarz): ~1.5e-5 => 16 quant units.
// MARGIN_Q = 128 (1.2e-4) gives >=8x headroom; ~200 points flagged.

#define MARGIN_Q 128u

__device__ __forceinline__ void async_load16(const void* g, void* l) {
    __builtin_amdgcn_global_load_lds(
        (const __attribute__((address_space(1))) unsigned int*)g,
        (__attribute__((address_space(3))) unsigned int*)l, 16, 0, 0);
}

__device__ __forceinline__ unsigned qdist(float d) {
    float t = (d + 1.0f) * 1048576.0f;          // dist in [-1,3] -> [0,2^22)
    t = fminf(fmaxf(t, 0.0f), 4194303.0f);
    return (unsigned)t;
}

__device__ __forceinline__ void top2_merge(unsigned& b, unsigned& s,
                                           unsigned ob, unsigned os) {
    unsigned nb = min(b, ob);
    unsigned ns = min(max(b, ob), min(s, os));
    b = nb; s = ns;
}

// ---- split latent -> normalized bf16 hi/lo, layout [n][384] ----
__global__ __launch_bounds__(256) void k_split(const float* __restrict__ latent,
                                               ushort* __restrict__ Ap) {
    __shared__ float xs[64 * 193];
    __shared__ float part[4 * 64];
    __shared__ float invs[64];
    const int tid = threadIdx.x;
    const int n0 = blockIdx.x * 64;
    const int b = n0 >> 12;
    const int hw0 = n0 & 4095;
    const int p = tid & 63;
    const int ph = tid >> 6;

    const float* base = latent + (size_t)b * DIMS * HW + hw0 + p;
    float ssq = 0.f;
    for (int i = 0; i < 48; ++i) {
        int cc = ph + i * 4;
        float v = base[(size_t)cc * HW];      // 64 lanes coalesced
        xs[p * 193 + cc] = v;
        ssq = fmaf(v, v, ssq);
    }
    part[ph * 64 + p] = ssq;
    __syncthreads();
    if (tid < 64) {
        float s = part[tid] + part[64 + tid] + part[128 + tid] + part[192 + tid];
        invs[tid] = 1.0f / (sqrtf(s) + 1e-8f);
    }
    __syncthreads();

    // write 3072 16B-units: u -> (p, ch); ch<24: hi, else lo
    uint4* out = (uint4*)Ap;
    for (int i = 0; i < 12; ++i) {
        int u = i * 256 + tid;
        int pp = u / 48;
        int ch = u % 48;
        int dd = (ch % 24) * 8;
        bool hi_region = ch < 24;
        float inv = invs[pp];
        unsigned w[4];
        #pragma unroll
        for (int j = 0; j < 4; ++j) {
            unsigned short h2[2];
            #pragma unroll
            for (int e = 0; e < 2; ++e) {
                float f = xs[pp * 193 + dd + j * 2 + e] * inv;
                __hip_bfloat16 h = __float2bfloat16(f);
                if (!hi_region) {
                    float r = f - __bfloat162float(h);
                    h = __float2bfloat16(r);
                }
                h2[e] = *(unsigned short*)&h;
            }
            w[j] = (unsigned)h2[0] | ((unsigned)h2[1] << 16);
        }
        out[(size_t)(n0) * 48 + u] = make_uint4(w[0], w[1], w[2], w[3]);
    }
}

// ---- split codebook -> bf16 hi/lo, layout [k][384] ----
__global__ __launch_bounds__(256) void k_prep_cb(const float* __restrict__ cbk,
                                                 ushort* __restrict__ Bp) {
    int u = blockIdx.x * 256 + threadIdx.x;     // 49152 units
    if (u >= KCB * 48) return;
    int k = u / 48;
    int ch = u % 48;
    int dd = (ch % 24) * 8;
    bool hi_region = ch < 24;
    const float* row = cbk + (size_t)k * DIMS + dd;
    unsigned w[4];
    #pragma unroll
    for (int j = 0; j < 4; ++j) {
        unsigned short h2[2];
        #pragma unroll
        for (int e = 0; e < 2; ++e) {
            float f = row[j * 2 + e];
            __hip_bfloat16 h = __float2bfloat16(f);
            if (!hi_region) {
                float r = f - __bfloat162float(h);
                h = __float2bfloat16(r);
            }
            h2[e] = *(unsigned short*)&h;
        }
        w[j] = (unsigned)h2[0] | ((unsigned)h2[1] << 16);
    }
    ((uint4*)Bp)[u] = make_uint4(w[0], w[1], w[2], w[3]);
}

// ---- codebook row squared norms ----
__global__ __launch_bounds__(256) void k_c2(const float* __restrict__ cbk,
                                            float* __restrict__ c2) {
    int k = blockIdx.x * 256 + threadIdx.x;
    if (k >= KCB) return;
    const float4* row = (const float4*)(cbk + (size_t)k * DIMS);
    float s = 0.f;
    #pragma unroll
    for (int i = 0; i < DIMS / 4; ++i) {
        float4 v = row[i];
        s += v.x * v.x + v.y * v.y + v.z * v.z + v.w * v.w;
    }
    c2[k] = s;
}

// ---- transpose codebook fp32: cbkT[d][k] (for coalesced rescore) ----
__global__ __launch_bounds__(256) void k_cbT(const float* __restrict__ cbk,
                                             float* __restrict__ cbkT) {
    __shared__ float q[64 * 193];
    const int tid = threadIdx.x;
    const int k0 = blockIdx.x * 64;
    const int lane = tid & 63;
    const int grp = tid >> 6;
    for (int r = grp; r < 64; r += 4) {
        const float* row = cbk + (size_t)(k0 + r) * DIMS;
        for (int c = lane; c < DIMS; c += 64) q[r * 193 + c] = row[c];
    }
    __syncthreads();
    for (int d = grp; d < DIMS; d += 4) {
        cbkT[(size_t)d * KCB + k0 + lane] = q[lane * 193 + d];
    }
}

// ---- MFMA distance GEMM + per-(point, nb) top-2 ----
// grid 4096 = 512 mblk (low bits) x 8 nb (high bits); 256 thr = 4 waves,
// wave tile 64x64 (4x4 of 16x16x32 bf16). LDS 128x64 bf16 per operand,
// XOR-swizzled 16B chunks (2-way bank conflicts only).
__global__ __launch_bounds__(256, 3) void k_gemm(const ushort* __restrict__ Ap,
                                                 const ushort* __restrict__ Bp,
                                                 const float* __restrict__ c2,
                                                 uint2* __restrict__ best2) {
    __shared__ __align__(16) ushort As[128 * 64];
    __shared__ __align__(16) ushort Bs[128 * 64];
    __shared__ uint2 t2buf[128 * 2];

    const int tid = threadIdx.x;
    const int wave = tid >> 6;
    const int lane = tid & 63;
    const int quad = lane >> 4;
    const int l15 = lane & 15;
    const int mblk = blockIdx.x & 511;
    const int nb = blockIdx.x >> 9;
    const int wm = (wave >> 1) * 64;
    const int wn = (wave & 1) * 64;

    f32x4 acc[4][4];
    #pragma unroll
    for (int mt = 0; mt < 4; ++mt)
        #pragma unroll
        for (int nt = 0; nt < 4; ++nt)
            #pragma unroll
            for (int r = 0; r < 4; ++r) acc[mt][nt][r] = 0.f;

    const size_t arow0 = (size_t)mblk * 128;
    const size_t brow0 = (size_t)nb * 128;

    for (int dc = 0; dc < 9; ++dc) {
        int ga = (dc < 3 ? dc : dc - 3) * 8;
        int gb = (dc < 6 ? dc : dc - 6) * 8;
        __syncthreads();
        #pragma unroll
        for (int i = 0; i < 4; ++i) {
            int u = i * 256 + tid;            // 0..1023 16B-units
            int m = u >> 3;
            int c = u & 7;
            int sw = c ^ (m & 7);
            async_load16(Ap + ((arow0 + m) * 48 + ga + sw) * 8, &As[u * 8]);
            async_load16(Bp + ((brow0 + m) * 48 + gb + sw) * 8, &Bs[u * 8]);
        }
        __syncthreads();
        #pragma unroll
        for (int s = 0; s < 2; ++s) {
            bf16x8 af[4], bfr[4];
            #pragma unroll
            for (int mt = 0; mt < 4; ++mt) {
                int m = wm + mt * 16 + l15;
                int c = (s * 4 + quad) ^ (m & 7);
                af[mt] = *(const bf16x8*)&As[m * 64 + c * 8];
            }
            #pragma unroll
            for (int nt = 0; nt < 4; ++nt) {
                int n = wn + nt * 16 + l15;
                int c = (s * 4 + quad) ^ (n & 7);
                bfr[nt] = *(const bf16x8*)&Bs[n * 64 + c * 8];
            }
            #pragma unroll
            for (int mt = 0; mt < 4; ++mt)
                #pragma unroll
                for (int nt = 0; nt < 4; ++nt)
                    acc[mt][nt] = __builtin_amdgcn_mfma_f32_16x16x32_bf16(
                        af[mt], bfr[nt], acc[mt][nt], 0, 0, 0);
        }
    }

    // epilogue: dist = c2[k] - 2*dot (x normalized); top-2 packed (q<<10)|k
    int kcol[4];
    float cc2[4];
    #pragma unroll
    for (int nt = 0; nt < 4; ++nt) {
        kcol[nt] = nb * 128 + wn + nt * 16 + l15;
        cc2[nt] = c2[kcol[nt]];
    }
    #pragma unroll
    for (int mt = 0; mt < 4; ++mt) {
        #pragma unroll
        for (int r = 0; r < 4; ++r) {
            unsigned p[4];
            #pragma unroll
            for (int nt = 0; nt < 4; ++nt) {
                float dist = fmaf(-2.f, acc[mt][nt][r], cc2[nt]);
                p[nt] = (qdist(dist) << 10) | (unsigned)kcol[nt];
            }
            unsigned b01 = min(p[0], p[1]), s01 = max(p[0], p[1]);
            unsigned b23 = min(p[2], p[3]), s23 = max(p[2], p[3]);
            unsigned b = min(b01, b23);
            unsigned s = min(max(b01, b23), min(s01, s23));
            #pragma unroll
            for (int off = 1; off < 16; off <<= 1) {
                unsigned ob = __shfl_xor(b, off, 64);
                unsigned os = __shfl_xor(s, off, 64);
                top2_merge(b, s, ob, os);
            }
            if (l15 == 0) {
                int mloc = wm + mt * 16 + quad * 4 + r;
                t2buf[mloc * 2 + (wave & 1)] = make_uint2(b, s);
            }
        }
    }
    __syncthreads();
    if (tid < 128) {
        uint2 x = t2buf[tid * 2];
        uint2 y = t2buf[tid * 2 + 1];
        unsigned b = x.x, s = x.y;
        top2_merge(b, s, y.x, y.y);
        best2[(arow0 + tid) * 8 + nb] = make_uint2(b, s);
    }
}

// ---- merge 8 nb-partials -> argmin; flag narrow-gap points ----
__global__ __launch_bounds__(256) void k_combine(const uint2* __restrict__ best2,
                                                 int* __restrict__ idx,
                                                 float* __restrict__ idxf,
                                                 int* __restrict__ list,
                                                 int* __restrict__ cnt) {
    int n = blockIdx.x * 256 + threadIdx.x;
    unsigned b = 0xFFFFFFFFu, s = 0xFFFFFFFFu;
    #pragma unroll
    for (int j = 0; j < 8; ++j) {
        uint2 v = best2[(size_t)n * 8 + j];
        top2_merge(b, s, v.x, v.y);
    }
    int k = (int)(b & 1023u);
    idx[n] = k;
    idxf[n] = (float)k;
    if (((s >> 10) - (b >> 10)) < MARGIN_Q) {
        int pos = atomicAdd(cnt, 1);
        list[pos] = n;
    }
}

// ---- exact fp32 rescore of flagged points (coalesced via cbkT) ----
// thread t owns codewords 4t..4t+3; one float4 load per d, L2-resident.
__global__ __launch_bounds__(256) void k_rescore(const float* __restrict__ latent,
                                                 const float* __restrict__ cbkT,
                                                 const float* __restrict__ c2,
                                                 const int* __restrict__ list,
                                                 const int* __restrict__ cnt,
                                                 int* __restrict__ idx,
                                                 float* __restrict__ idxf) {
    __shared__ float xs[DIMS];
    __shared__ float red[256];
    __shared__ float sinv_sh;
    __shared__ unsigned long long best;
    const int tid = threadIdx.x;
    const int count = *cnt;
    const float4* ct = (const float4*)cbkT;     // [d][256] float4

    for (int fi = blockIdx.x; fi < count; fi += gridDim.x) {
        int n = list[fi];
        int b = n >> 12, hw = n & 4095;
        __syncthreads();
        float v = 0.f;
        if (tid < DIMS) {
            v = latent[((size_t)b * DIMS + tid) * HW + hw];
            xs[tid] = v;
        }
        red[tid] = v * v;
        if (tid == 0) best = ~0ull;
        __syncthreads();
        #pragma unroll
        for (int off = 128; off > 0; off >>= 1) {
            if (tid < off) red[tid] += red[tid + off];
            __syncthreads();
        }
        if (tid == 0) sinv_sh = 1.0f / (sqrtf(red[0]) + 1e-8f);
        __syncthreads();
        float inv = sinv_sh;

        float4 acc = make_float4(0.f, 0.f, 0.f, 0.f);
        #pragma unroll 4
        for (int d = 0; d < DIMS; ++d) {
            float xv = xs[d];
            float4 cv = ct[(size_t)d * 256 + tid];
            acc.x = fmaf(xv, cv.x, acc.x);
            acc.y = fmaf(xv, cv.y, acc.y);
            acc.z = fmaf(xv, cv.z, acc.z);
            acc.w = fmaf(xv, cv.w, acc.w);
        }
        float dot4[4] = {acc.x, acc.y, acc.z, acc.w};
        unsigned long long loc = ~0ull;
        #pragma unroll
        for (int e = 0; e < 4; ++e) {
            int k = 4 * tid + e;
            float dist = c2[k] - 2.f * inv * dot4[e];
            unsigned ub = __float_as_uint(dist);
            ub ^= (ub >> 31) ? 0xFFFFFFFFu : 0x80000000u;   // monotonic map
            unsigned long long pk = ((unsigned long long)ub << 32) | (unsigned)k;
            loc = loc < pk ? loc : pk;
        }
        atomicMin(&best, loc);
        __syncthreads();
        if (tid == 0) {
            int k = (int)(best & 0xFFFFFFFFull);
            idx[n] = k;
            idxf[n] = (float)k;
        }
    }
}

// ---- gather + transpose to [B,C,H,W] ----
__global__ __launch_bounds__(256) void k_gather(const float* __restrict__ cbk,
                                                const int* __restrict__ idx,
                                                float* __restrict__ out) {
    __shared__ float q[64 * 193];
    __shared__ int sidx[64];
    const int tid = threadIdx.x;
    const int n0 = blockIdx.x * 64;
    const int b = n0 >> 12;
    const int hw0 = n0 & 4095;
    const int lane = tid & 63;
    const int grp = tid >> 6;

    if (tid < 64) sidx[tid] = idx[n0 + tid];
    __syncthreads();
    for (int r = grp; r < 64; r += 4) {
        const float* row = cbk + (size_t)sidx[r] * DIMS;
        for (int c = lane; c < DIMS; c += 64) q[r * 193 + c] = row[c];
    }
    __syncthreads();
    float* obase = out + (size_t)b * DIMS * HW + hw0;
    for (int c = grp; c < DIMS; c += 4) {
        obase[(size_t)c * HW + lane] = q[lane * 193 + c];
    }
}

// ======================= fallback fp32 path (round-1) ====================
__global__ __launch_bounds__(256) void k_norms_fb(const float* __restrict__ latent,
                                                  float* __restrict__ inv_norm) {
    __shared__ float red[256];
    const int tid = threadIdx.x;
    const int n0 = blockIdx.x * 128;
    const int nl = tid & 127;
    const int half = tid >> 7;
    const int b = n0 >> 12;
    const int hw = (n0 & 4095) + nl;
    const float* base = latent + (size_t)b * DIMS * HW + hw;
    float ssq = 0.f;
    for (int c = half; c < DIMS; c += 2) {
        float v = base[(size_t)c * HW];
        ssq = fmaf(v, v, ssq);
    }
    red[tid] = ssq;
    __syncthreads();
    if (half == 0) {
        float s = red[tid] + red[tid + 128];
        inv_norm[n0 + nl] = 1.0f / (sqrtf(s) + 1e-8f);
    }
}

#define LDX  132
__global__ __launch_bounds__(256) void k_dist_fb(const float* __restrict__ latent,
                                                 const float* __restrict__ cbk,
                                                 const float* __restrict__ inv_norm,
                                                 const float* __restrict__ c2,
                                                 int* __restrict__ idx_out,
                                                 float* __restrict__ idxf_out) {
    __shared__ __align__(16) float xsm[64 * LDX];
    __shared__ __align__(16) float csm[64 * LDX];
    __shared__ unsigned long long red[128];
    const int tid = threadIdx.x;
    const int n0 = blockIdx.x * 128;
    const int b = n0 >> 12;
    const int hw0 = n0 & 4095;
    const int kt = tid & 15;
    const int mt = tid >> 4;
    const float* lat_base = latent + (size_t)b * DIMS * HW + hw0;
    float inv[8];
    #pragma unroll
    for (int i = 0; i < 8; ++i) inv[i] = inv_norm[n0 + mt * 8 + i];
    float best[8];
    int bidx[8];
    #pragma unroll
    for (int i = 0; i < 8; ++i) { best[i] = 3.4e38f; bidx[i] = 0; }
    const int nl = tid & 127;
    const int cp = tid >> 7;
    for (int k0 = 0; k0 < KCB; k0 += 128) {
        float acc[8][8];
        #pragma unroll
        for (int i = 0; i < 8; ++i)
            #pragma unroll
            for (int j = 0; j < 8; ++j) acc[i][j] = 0.f;
        for (int d0 = 0; d0 < DIMS; d0 += 64) {
            __syncthreads();
            for (int cc = cp; cc < 64; cc += 2)
                xsm[cc * LDX + nl] = lat_base[(size_t)(d0 + cc) * HW + nl];
            #pragma unroll
            for (int i = 0; i < 8; ++i) {
                int f4 = tid + 256 * i;
                int kk = f4 >> 4;
                int dq = f4 & 15;
                float4 v = *(const float4*)(cbk + (size_t)(k0 + kk) * DIMS + d0 + dq * 4);
                csm[(dq * 4 + 0) * LDX + kk] = v.x;
                csm[(dq * 4 + 1) * LDX + kk] = v.y;
                csm[(dq * 4 + 2) * LDX + kk] = v.z;
                csm[(dq * 4 + 3) * LDX + kk] = v.w;
            }
            __syncthreads();
            for (int d = 0; d < 64; ++d) {
                const float* xr = &xsm[d * LDX + mt * 8];
                const float* cr = &csm[d * LDX + kt * 8];
                float x8[8], c8[8];
                *(float4*)&x8[0] = *(const float4*)&xr[0];
                *(float4*)&x8[4] = *(const float4*)&xr[4];
                *(float4*)&c8[0] = *(const float4*)&cr[0];
                *(float4*)&c8[4] = *(const float4*)&cr[4];
                #pragma unroll
                for (int i = 0; i < 8; ++i)
                    #pragma unroll
                    for (int j = 0; j < 8; ++j)
                        acc[i][j] = fmaf(x8[i], c8[j], acc[i][j]);
            }
        }
        float cc2[8];
        #pragma unroll
        for (int j = 0; j < 8; ++j) cc2[j] = c2[k0 + kt * 8 + j];
        #pragma unroll
        for (int i = 0; i < 8; ++i)
            #pragma unroll
            for (int j = 0; j < 8; ++j) {
                float t = inv[i] * acc[i][j];
                float dist = fmaf(-2.f, t, cc2[j]);
                int kidx = k0 + kt * 8 + j;
                if (dist < best[i]) { best[i] = dist; bidx[i] = kidx; }
            }
    }
    if (tid < 128) red[tid] = ~0ull;
    __syncthreads();
    #pragma unroll
    for (int i = 0; i < 8; ++i) {
        unsigned long long p =
            ((unsigned long long)__float_as_uint(best[i]) << 32) | (unsigned)bidx[i];
        atomicMin(&red[mt * 8 + i], p);
    }
    __syncthreads();
    if (tid < 128) {
        int k = (int)(red[tid] & 0xFFFFFFFFu);
        idx_out[n0 + tid] = k;
        idxf_out[n0 + tid] = (float)k;
    }
}

// ================================ launch ================================
extern "C" void kernel_launch(void* const* d_in, const int* in_sizes, int n_in,
                              void* d_out, int out_size, void* d_ws, size_t ws_size,
                              hipStream_t stream) {
    const float* latent = (const float*)d_in[0];
    const float* cbk = (const float*)d_in[1];
    float* out = (float*)d_out;
    float* out_q = out;
    float* out_idx = out + QELEMS;

    if (ws_size >= 56u * 1024u * 1024u) {
        // ws layout (bytes):
        char* w = (char*)d_ws;
        ushort* Ap = (ushort*)w;                               // 50,331,648
        ushort* Bp = (ushort*)(w + 50331648);                  //    786,432
        float* cbkT = (float*)(w + 51118080);                  //    786,432
        float* c2 = (float*)(w + 51904512);                    //      4,096
        uint2* best2 = (uint2*)(w + 51908608);                 //  4,194,304
        int* idx = (int*)(w + 56102912);                       //    262,144
        int* list = (int*)(w + 56365056);                      //    262,144
        int* cnt = (int*)(w + 56627200);                       //          4

        hipMemsetAsync(cnt, 0, 4, stream);
        k_split<<<NPTS / 64, 256, 0, stream>>>(latent, Ap);
        k_prep_cb<<<192, 256, 0, stream>>>(cbk, Bp);
        k_c2<<<4, 256, 0, stream>>>(cbk, c2);
        k_cbT<<<KCB / 64, 256, 0, stream>>>(cbk, cbkT);
        k_gemm<<<4096, 256, 0, stream>>>(Ap, Bp, c2, best2);
        k_combine<<<256, 256, 0, stream>>>(best2, idx, out_idx, list, cnt);
        k_rescore<<<512, 256, 0, stream>>>(latent, cbkT, c2, list, cnt, idx, out_idx);
        k_gather<<<NPTS / 64, 256, 0, stream>>>(cbk, idx, out_q);
    } else {
        float* inv_norm = (float*)d_ws;
        float* c2 = inv_norm + NPTS;
        int* idx = (int*)(c2 + KCB);
        k_norms_fb<<<NPTS / 128, 256, 0, stream>>>(latent, inv_norm);
        k_c2<<<4, 256, 0, stream>>>(cbk, c2);
        k_dist_fb<<<NPTS / 128, 256, 0, stream>>>(latent, cbk, inv_norm, c2, idx, out_idx);
        k_gather<<<NPTS / 64, 256, 0, stream>>>(cbk, idx, out_q);
    }
}

// Round 4
// 252.009 us; speedup vs baseline: 2.0926x; 1.1477x over previous
//
#include <hip/hip_runtime.h>
#include <hip/hip_bf16.h>

// Problem: latent (16,192,64,64) fp32, codebook (1024,192) fp32.
// N = 65536 points, D = 192, K = 1024.
// d_out = [quantized: 12582912 fp32][indices-as-float: 65536].

#define NPTS   65536
#define DIMS   192
#define KCB    1024
#define HW     4096
#define QELEMS 12582912

typedef __attribute__((ext_vector_type(8))) short bf16x8;
typedef __attribute__((ext_vector_type(4))) float f32x4;

// ============================ MFMA path =================================
// Split layouts (group-major for contiguous 16 KB tile staging):
//   Ap[g][n][8 u4]: g 0-2 = hi dims g*64..g*64+63, g 3-5 = lo dims (g-3)*64..
//   Bp[g][k][8 u4]: same group mapping.
// Per dim-group g, three bf16 GEMM terms: Ah*Bh + Ah*Bl + Al*Bh
//   => dot ~ xh*ch + xh*cl + xl*ch   (worst-case dist err ~1.5e-5)
// MARGIN_Q = 128 (1.2e-4 on the 2^-20 quant grid) -> >=8x headroom;
// ~200 narrow-gap points get exact fp32 rescore.

#define MARGIN_Q 128u

__device__ __forceinline__ void async_load16(const void* g, void* l) {
    __builtin_amdgcn_global_load_lds(
        (const __attribute__((address_space(1))) unsigned int*)g,
        (__attribute__((address_space(3))) unsigned int*)l, 16, 0, 0);
}

__device__ __forceinline__ unsigned qdist(float d) {
    float t = (d + 1.0f) * 1048576.0f;          // dist in [-1,3] -> [0,2^22)
    t = fminf(fmaxf(t, 0.0f), 4194303.0f);
    return (unsigned)t;
}

__device__ __forceinline__ void top2_merge(unsigned& b, unsigned& s,
                                           unsigned ob, unsigned os) {
    unsigned nb = min(b, ob);
    unsigned ns = min(max(b, ob), min(s, os));
    b = nb; s = ns;
}

// ---- split latent -> normalized bf16 hi/lo, group-major layout ----
__global__ __launch_bounds__(256) void k_split(const float* __restrict__ latent,
                                               ushort* __restrict__ Ap) {
    __shared__ float xs[64 * 193];
    __shared__ float part[4 * 64];
    __shared__ float invs[64];
    const int tid = threadIdx.x;
    const int n0 = blockIdx.x * 64;
    const int b = n0 >> 12;
    const int hw0 = n0 & 4095;
    const int p = tid & 63;
    const int ph = tid >> 6;

    const float* base = latent + (size_t)b * DIMS * HW + hw0 + p;
    float ssq = 0.f;
    for (int i = 0; i < 48; ++i) {
        int cc = ph + i * 4;
        float v = base[(size_t)cc * HW];      // 64 lanes coalesced
        xs[p * 193 + cc] = v;
        ssq = fmaf(v, v, ssq);
    }
    part[ph * 64 + p] = ssq;
    __syncthreads();
    if (tid < 64) {
        float s = part[tid] + part[64 + tid] + part[128 + tid] + part[192 + tid];
        invs[tid] = 1.0f / (sqrtf(s) + 1e-8f);
    }
    __syncthreads();

    // 3072 u4 per block: u -> (g, p, c); dims dd..dd+7, hi if g<3
    uint4* out = (uint4*)Ap;
    for (int i = 0; i < 12; ++i) {
        int u = i * 256 + tid;
        int g = u >> 9;
        int rem = u & 511;
        int pp = rem >> 3;
        int c = rem & 7;
        int dd = ((g % 3) * 8 + c) * 8;
        bool hi_region = g < 3;
        float inv = invs[pp];
        unsigned w[4];
        #pragma unroll
        for (int j = 0; j < 4; ++j) {
            unsigned short h2[2];
            #pragma unroll
            for (int e = 0; e < 2; ++e) {
                float f = xs[pp * 193 + dd + j * 2 + e] * inv;
                __hip_bfloat16 h = __float2bfloat16(f);
                if (!hi_region) {
                    float r = f - __bfloat162float(h);
                    h = __float2bfloat16(r);
                }
                h2[e] = *(unsigned short*)&h;
            }
            w[j] = (unsigned)h2[0] | ((unsigned)h2[1] << 16);
        }
        out[(size_t)(g * NPTS + n0 + pp) * 8 + c] = make_uint4(w[0], w[1], w[2], w[3]);
    }
}

// ---- split codebook -> bf16 hi/lo, group-major layout ----
__global__ __launch_bounds__(256) void k_prep_cb(const float* __restrict__ cbk,
                                                 ushort* __restrict__ Bp) {
    int u = blockIdx.x * 256 + threadIdx.x;     // 49152 u4
    if (u >= KCB * 48) return;
    int g = u / 8192;
    int rem = u % 8192;
    int k = rem >> 3;
    int c = rem & 7;
    int dd = ((g % 3) * 8 + c) * 8;
    bool hi_region = g < 3;
    const float* row = cbk + (size_t)k * DIMS + dd;
    unsigned w[4];
    #pragma unroll
    for (int j = 0; j < 4; ++j) {
        unsigned short h2[2];
        #pragma unroll
        for (int e = 0; e < 2; ++e) {
            float f = row[j * 2 + e];
            __hip_bfloat16 h = __float2bfloat16(f);
            if (!hi_region) {
                float r = f - __bfloat162float(h);
                h = __float2bfloat16(r);
            }
            h2[e] = *(unsigned short*)&h;
        }
        w[j] = (unsigned)h2[0] | ((unsigned)h2[1] << 16);
    }
    ((uint4*)Bp)[(size_t)(g * KCB + k) * 8 + c] = make_uint4(w[0], w[1], w[2], w[3]);
}

// ---- codebook row squared norms ----
__global__ __launch_bounds__(256) void k_c2(const float* __restrict__ cbk,
                                            float* __restrict__ c2) {
    int k = blockIdx.x * 256 + threadIdx.x;
    if (k >= KCB) return;
    const float4* row = (const float4*)(cbk + (size_t)k * DIMS);
    float s = 0.f;
    #pragma unroll
    for (int i = 0; i < DIMS / 4; ++i) {
        float4 v = row[i];
        s += v.x * v.x + v.y * v.y + v.z * v.z + v.w * v.w;
    }
    c2[k] = s;
}

// ---- transpose codebook fp32: cbkT[d][k] (for coalesced rescore) ----
__global__ __launch_bounds__(256) void k_cbT(const float* __restrict__ cbk,
                                             float* __restrict__ cbkT) {
    __shared__ float q[64 * 193];
    const int tid = threadIdx.x;
    const int k0 = blockIdx.x * 64;
    const int lane = tid & 63;
    const int grp = tid >> 6;
    for (int r = grp; r < 64; r += 4) {
        const float* row = cbk + (size_t)(k0 + r) * DIMS;
        for (int c = lane; c < DIMS; c += 64) q[r * 193 + c] = row[c];
    }
    __syncthreads();
    for (int d = grp; d < DIMS; d += 4) {
        cbkT[(size_t)d * KCB + k0 + lane] = q[lane * 193 + d];
    }
}

// ---- fused MFMA distance GEMM + in-block argmin + gather epilogue ----
// grid 512 (128 points each); 256 thr = 4 waves (2x2 of 64x64 MFMA tiles).
// nb loop (8 x 128 codewords) inside; per dim-group g stage Ah/Al/Bh/Bl
// (64 KB) once and run all 3 precision terms (96 MFMA/wave per barrier).
__global__ __launch_bounds__(256, 2) void k_gemm(const ushort* __restrict__ Ap,
                                                 const ushort* __restrict__ Bp,
                                                 const float* __restrict__ c2,
                                                 const float* __restrict__ cbk,
                                                 float* __restrict__ out_q,
                                                 float* __restrict__ idxf,
                                                 int* __restrict__ list,
                                                 int* __restrict__ cnt) {
    __shared__ __align__(16) char smem[65536];
    ushort* Ah = (ushort*)smem;                 // 16 KB  (K-loop)
    ushort* Bh = (ushort*)(smem + 16384);       // 16 KB
    ushort* Al = (ushort*)(smem + 32768);       // 16 KB
    ushort* Bl = (ushort*)(smem + 49152);       // 16 KB
    uint2* t2buf = (uint2*)(smem + 49152);      // 2 KB   (post-K-loop, in Bl)
    int* sidx = (int*)(smem + 52224);           // 512 B  (post-K-loop)
    float* q = (float*)smem;                    // 24.7 KB (gather phase)

    const int tid = threadIdx.x;
    const int wave = tid >> 6;
    const int lane = tid & 63;
    const int quad = lane >> 4;
    const int l15 = lane & 15;
    const int wm = (wave >> 1) * 64;
    const int wn = (wave & 1) * 64;
    const int n0 = blockIdx.x * 128;
    const size_t arow0 = (size_t)n0;

    unsigned rb[16], rs[16];
    #pragma unroll
    for (int i = 0; i < 16; ++i) { rb[i] = 0xFFFFFFFFu; rs[i] = 0xFFFFFFFFu; }

    for (int nb = 0; nb < 8; ++nb) {
        f32x4 acc[4][4];
        #pragma unroll
        for (int mt = 0; mt < 4; ++mt)
            #pragma unroll
            for (int nt = 0; nt < 4; ++nt)
                #pragma unroll
                for (int r = 0; r < 4; ++r) acc[mt][nt][r] = 0.f;

        const size_t brow0 = (size_t)nb * 128;

        for (int g = 0; g < 3; ++g) {
            __syncthreads();
            #pragma unroll
            for (int i = 0; i < 4; ++i) {
                int u = i * 256 + tid;          // 1024 u4 per tile
                int m = u >> 3, c = u & 7;
                int sw = c ^ (m & 7);           // XOR swizzle (2-way max)
                async_load16(Ap + (((size_t)g * NPTS + arow0 + m) * 8 + sw) * 8, &Ah[u * 8]);
                async_load16(Ap + (((size_t)(g + 3) * NPTS + arow0 + m) * 8 + sw) * 8, &Al[u * 8]);
                async_load16(Bp + (((size_t)g * KCB + brow0 + m) * 8 + sw) * 8, &Bh[u * 8]);
                async_load16(Bp + (((size_t)(g + 3) * KCB + brow0 + m) * 8 + sw) * 8, &Bl[u * 8]);
            }
            __syncthreads();
            #pragma unroll
            for (int s = 0; s < 2; ++s) {
                bf16x8 fah[4], fal[4], fbh[4], fbl[4];
                #pragma unroll
                for (int mt = 0; mt < 4; ++mt) {
                    int m = wm + mt * 16 + l15;
                    int c = (s * 4 + quad) ^ (m & 7);
                    fah[mt] = *(const bf16x8*)&Ah[m * 64 + c * 8];
                    fal[mt] = *(const bf16x8*)&Al[m * 64 + c * 8];
                }
                #pragma unroll
                for (int nt = 0; nt < 4; ++nt) {
                    int n = wn + nt * 16 + l15;
                    int c = (s * 4 + quad) ^ (n & 7);
                    fbh[nt] = *(const bf16x8*)&Bh[n * 64 + c * 8];
                    fbl[nt] = *(const bf16x8*)&Bl[n * 64 + c * 8];
                }
                #pragma unroll
                for (int mt = 0; mt < 4; ++mt)
                    #pragma unroll
                    for (int nt = 0; nt < 4; ++nt) {
                        acc[mt][nt] = __builtin_amdgcn_mfma_f32_16x16x32_bf16(
                            fah[mt], fbh[nt], acc[mt][nt], 0, 0, 0);
                        acc[mt][nt] = __builtin_amdgcn_mfma_f32_16x16x32_bf16(
                            fah[mt], fbl[nt], acc[mt][nt], 0, 0, 0);
                        acc[mt][nt] = __builtin_amdgcn_mfma_f32_16x16x32_bf16(
                            fal[mt], fbh[nt], acc[mt][nt], 0, 0, 0);
                    }
            }
        }

        // per-nb epilogue: merge this 128-col strip into running top-2
        int kbase = nb * 128 + wn;
        float c2v[4];
        #pragma unroll
        for (int nt = 0; nt < 4; ++nt) c2v[nt] = c2[kbase + nt * 16 + l15];
        #pragma unroll
        for (int mt = 0; mt < 4; ++mt) {
            #pragma unroll
            for (int r = 0; r < 4; ++r) {
                unsigned p[4];
                #pragma unroll
                for (int nt = 0; nt < 4; ++nt) {
                    float dist = fmaf(-2.f, acc[mt][nt][r], c2v[nt]);
                    p[nt] = (qdist(dist) << 10) | (unsigned)(kbase + nt * 16 + l15);
                }
                unsigned b01 = min(p[0], p[1]), s01 = max(p[0], p[1]);
                unsigned b23 = min(p[2], p[3]), s23 = max(p[2], p[3]);
                unsigned nbb = min(b01, b23);
                unsigned nbs = min(max(b01, b23), min(s01, s23));
                top2_merge(rb[mt * 4 + r], rs[mt * 4 + r], nbb, nbs);
            }
        }
    }

    __syncthreads();   // all waves done with tiles before t2buf reuses Bl
    #pragma unroll
    for (int i = 0; i < 16; ++i) {
        unsigned b = rb[i], s = rs[i];
        #pragma unroll
        for (int off = 1; off < 16; off <<= 1) {
            unsigned ob = __shfl_xor(b, off, 64);
            unsigned os = __shfl_xor(s, off, 64);
            top2_merge(b, s, ob, os);
        }
        if (l15 == 0) {
            int mt = i >> 2, r = i & 3;
            int mloc = wm + mt * 16 + quad * 4 + r;
            t2buf[mloc * 2 + (wave & 1)] = make_uint2(b, s);
        }
    }
    __syncthreads();
    if (tid < 128) {
        uint2 x = t2buf[tid * 2];
        uint2 y = t2buf[tid * 2 + 1];
        unsigned b = x.x, s = x.y;
        top2_merge(b, s, y.x, y.y);
        int k = (int)(b & 1023u);
        sidx[tid] = k;
        idxf[n0 + tid] = (float)k;
        if (((s >> 10) - (b >> 10)) < MARGIN_Q) {
            int pos = atomicAdd(cnt, 1);
            list[pos] = n0 + tid;
        }
    }
    __syncthreads();

    // gather epilogue: 4 chunks x 32 points, LDS-transposed coalesced write
    const int bB = n0 >> 12;
    const int hw0 = n0 & 4095;
    for (int chk = 0; chk < 4; ++chk) {
        int p0 = chk * 32;
        for (int r = wave; r < 32; r += 4) {
            const float* row = cbk + (size_t)sidx[p0 + r] * DIMS;
            for (int c = lane; c < DIMS; c += 64) q[r * 193 + c] = row[c];
        }
        __syncthreads();
        float* ob = out_q + (size_t)bB * DIMS * HW + hw0 + p0;
        #pragma unroll
        for (int i = 0; i < 24; ++i) {
            int u = i * 256 + tid;              // 6144 elements
            int c = u >> 5, p = u & 31;
            ob[(size_t)c * HW + p] = q[p * 193 + c];
        }
        __syncthreads();
    }
}

// ---- exact fp32 rescore of flagged points (writes idx + quantized row) ----
__global__ __launch_bounds__(256) void k_rescore(const float* __restrict__ latent,
                                                 const float* __restrict__ cbkT,
                                                 const float* __restrict__ cbk,
                                                 const float* __restrict__ c2,
                                                 const int* __restrict__ list,
                                                 const int* __restrict__ cnt,
                                                 float* __restrict__ out_q,
                                                 float* __restrict__ idxf) {
    __shared__ float xs[DIMS];
    __shared__ float red[256];
    __shared__ float sinv_sh;
    __shared__ unsigned long long best;
    const int tid = threadIdx.x;
    const int count = *cnt;
    const float4* ct = (const float4*)cbkT;     // [d][256] float4

    for (int fi = blockIdx.x; fi < count; fi += gridDim.x) {
        int n = list[fi];
        int bpt = n >> 12, hw = n & 4095;
        __syncthreads();
        float v = 0.f;
        if (tid < DIMS) {
            v = latent[((size_t)bpt * DIMS + tid) * HW + hw];
            xs[tid] = v;
        }
        red[tid] = v * v;
        if (tid == 0) best = ~0ull;
        __syncthreads();
        #pragma unroll
        for (int off = 128; off > 0; off >>= 1) {
            if (tid < off) red[tid] += red[tid + off];
            __syncthreads();
        }
        if (tid == 0) sinv_sh = 1.0f / (sqrtf(red[0]) + 1e-8f);
        __syncthreads();
        float inv = sinv_sh;

        float4 acc = make_float4(0.f, 0.f, 0.f, 0.f);
        #pragma unroll 4
        for (int d = 0; d < DIMS; ++d) {
            float xv = xs[d];
            float4 cv = ct[(size_t)d * 256 + tid];
            acc.x = fmaf(xv, cv.x, acc.x);
            acc.y = fmaf(xv, cv.y, acc.y);
            acc.z = fmaf(xv, cv.z, acc.z);
            acc.w = fmaf(xv, cv.w, acc.w);
        }
        float dot4[4] = {acc.x, acc.y, acc.z, acc.w};
        unsigned long long loc = ~0ull;
        #pragma unroll
        for (int e = 0; e < 4; ++e) {
            int k = 4 * tid + e;
            float dist = c2[k] - 2.f * inv * dot4[e];
            unsigned ub = __float_as_uint(dist);
            ub ^= (ub >> 31) ? 0xFFFFFFFFu : 0x80000000u;   // monotonic map
            unsigned long long pk = ((unsigned long long)ub << 32) | (unsigned)k;
            loc = loc < pk ? loc : pk;
        }
        atomicMin(&best, loc);
        __syncthreads();
        int kk = (int)(best & 0xFFFFFFFFull);
        if (tid == 0) idxf[n] = (float)kk;
        if (tid < DIMS)
            out_q[((size_t)bpt * DIMS + tid) * HW + hw] = cbk[(size_t)kk * DIMS + tid];
    }
}

// ---- gather (fallback path only) ----
__global__ __launch_bounds__(256) void k_gather(const float* __restrict__ cbk,
                                                const int* __restrict__ idx,
                                                float* __restrict__ out) {
    __shared__ float q[64 * 193];
    __shared__ int sidx[64];
    const int tid = threadIdx.x;
    const int n0 = blockIdx.x * 64;
    const int b = n0 >> 12;
    const int hw0 = n0 & 4095;
    const int lane = tid & 63;
    const int grp = tid >> 6;

    if (tid < 64) sidx[tid] = idx[n0 + tid];
    __syncthreads();
    for (int r = grp; r < 64; r += 4) {
        const float* row = cbk + (size_t)sidx[r] * DIMS;
        for (int c = lane; c < DIMS; c += 64) q[r * 193 + c] = row[c];
    }
    __syncthreads();
    float* obase = out + (size_t)b * DIMS * HW + hw0;
    for (int c = grp; c < DIMS; c += 4) {
        obase[(size_t)c * HW + lane] = q[lane * 193 + c];
    }
}

// ======================= fallback fp32 path (round-1) ====================
__global__ __launch_bounds__(256) void k_norms_fb(const float* __restrict__ latent,
                                                  float* __restrict__ inv_norm) {
    __shared__ float red[256];
    const int tid = threadIdx.x;
    const int n0 = blockIdx.x * 128;
    const int nl = tid & 127;
    const int half = tid >> 7;
    const int b = n0 >> 12;
    const int hw = (n0 & 4095) + nl;
    const float* base = latent + (size_t)b * DIMS * HW + hw;
    float ssq = 0.f;
    for (int c = half; c < DIMS; c += 2) {
        float v = base[(size_t)c * HW];
        ssq = fmaf(v, v, ssq);
    }
    red[tid] = ssq;
    __syncthreads();
    if (half == 0) {
        float s = red[tid] + red[tid + 128];
        inv_norm[n0 + nl] = 1.0f / (sqrtf(s) + 1e-8f);
    }
}

#define LDX  132
__global__ __launch_bounds__(256) void k_dist_fb(const float* __restrict__ latent,
                                                 const float* __restrict__ cbk,
                                                 const float* __restrict__ inv_norm,
                                                 const float* __restrict__ c2,
                                                 int* __restrict__ idx_out,
                                                 float* __restrict__ idxf_out) {
    __shared__ __align__(16) float xsm[64 * LDX];
    __shared__ __align__(16) float csm[64 * LDX];
    __shared__ unsigned long long red[128];
    const int tid = threadIdx.x;
    const int n0 = blockIdx.x * 128;
    const int b = n0 >> 12;
    const int hw0 = n0 & 4095;
    const int kt = tid & 15;
    const int mt = tid >> 4;
    const float* lat_base = latent + (size_t)b * DIMS * HW + hw0;
    float inv[8];
    #pragma unroll
    for (int i = 0; i < 8; ++i) inv[i] = inv_norm[n0 + mt * 8 + i];
    float best[8];
    int bidx[8];
    #pragma unroll
    for (int i = 0; i < 8; ++i) { best[i] = 3.4e38f; bidx[i] = 0; }
    const int nl = tid & 127;
    const int cp = tid >> 7;
    for (int k0 = 0; k0 < KCB; k0 += 128) {
        float acc[8][8];
        #pragma unroll
        for (int i = 0; i < 8; ++i)
            #pragma unroll
            for (int j = 0; j < 8; ++j) acc[i][j] = 0.f;
        for (int d0 = 0; d0 < DIMS; d0 += 64) {
            __syncthreads();
            for (int cc = cp; cc < 64; cc += 2)
                xsm[cc * LDX + nl] = lat_base[(size_t)(d0 + cc) * HW + nl];
            #pragma unroll
            for (int i = 0; i < 8; ++i) {
                int f4 = tid + 256 * i;
                int kk = f4 >> 4;
                int dq = f4 & 15;
                float4 v = *(const float4*)(cbk + (size_t)(k0 + kk) * DIMS + d0 + dq * 4);
                csm[(dq * 4 + 0) * LDX + kk] = v.x;
                csm[(dq * 4 + 1) * LDX + kk] = v.y;
                csm[(dq * 4 + 2) * LDX + kk] = v.z;
                csm[(dq * 4 + 3) * LDX + kk] = v.w;
            }
            __syncthreads();
            for (int d = 0; d < 64; ++d) {
                const float* xr = &xsm[d * LDX + mt * 8];
                const float* cr = &csm[d * LDX + kt * 8];
                float x8[8], c8[8];
                *(float4*)&x8[0] = *(const float4*)&xr[0];
                *(float4*)&x8[4] = *(const float4*)&xr[4];
                *(float4*)&c8[0] = *(const float4*)&cr[0];
                *(float4*)&c8[4] = *(const float4*)&cr[4];
                #pragma unroll
                for (int i = 0; i < 8; ++i)
                    #pragma unroll
                    for (int j = 0; j < 8; ++j)
                        acc[i][j] = fmaf(x8[i], c8[j], acc[i][j]);
            }
        }
        float cc2[8];
        #pragma unroll
        for (int j = 0; j < 8; ++j) cc2[j] = c2[k0 + kt * 8 + j];
        #pragma unroll
        for (int i = 0; i < 8; ++i)
            #pragma unroll
            for (int j = 0; j < 8; ++j) {
                float t = inv[i] * acc[i][j];
                float dist = fmaf(-2.f, t, cc2[j]);
                int kidx = k0 + kt * 8 + j;
                if (dist < best[i]) { best[i] = dist; bidx[i] = kidx; }
            }
    }
    if (tid < 128) red[tid] = ~0ull;
    __syncthreads();
    #pragma unroll
    for (int i = 0; i < 8; ++i) {
        unsigned long long p =
            ((unsigned long long)__float_as_uint(best[i]) << 32) | (unsigned)bidx[i];
        atomicMin(&red[mt * 8 + i], p);
    }
    __syncthreads();
    if (tid < 128) {
        int k = (int)(red[tid] & 0xFFFFFFFFu);
        idx_out[n0 + tid] = k;
        idxf_out[n0 + tid] = (float)k;
    }
}

// ================================ launch ================================
extern "C" void kernel_launch(void* const* d_in, const int* in_sizes, int n_in,
                              void* d_out, int out_size, void* d_ws, size_t ws_size,
                              hipStream_t stream) {
    const float* latent = (const float*)d_in[0];
    const float* cbk = (const float*)d_in[1];
    float* out = (float*)d_out;
    float* out_q = out;
    float* out_idx = out + QELEMS;

    if (ws_size >= 53u * 1024u * 1024u) {
        // ws layout (bytes):
        char* w = (char*)d_ws;
        ushort* Ap = (ushort*)w;                               // 50,331,648
        ushort* Bp = (ushort*)(w + 50331648);                  //    786,432
        float* cbkT = (float*)(w + 51118080);                  //    786,432
        float* c2 = (float*)(w + 51904512);                    //      4,096
        int* list = (int*)(w + 51908608);                      //    262,144
        int* cnt = (int*)(w + 52170752);                       //          4

        hipMemsetAsync(cnt, 0, 4, stream);
        k_split<<<NPTS / 64, 256, 0, stream>>>(latent, Ap);
        k_prep_cb<<<192, 256, 0, stream>>>(cbk, Bp);
        k_c2<<<4, 256, 0, stream>>>(cbk, c2);
        k_cbT<<<KCB / 64, 256, 0, stream>>>(cbk, cbkT);
        k_gemm<<<512, 256, 0, stream>>>(Ap, Bp, c2, cbk, out_q, out_idx, list, cnt);
        k_rescore<<<512, 256, 0, stream>>>(latent, cbkT, cbk, c2, list, cnt, out_q, out_idx);
    } else {
        float* inv_norm = (float*)d_ws;
        float* c2 = inv_norm + NPTS;
        int* idx = (int*)(c2 + KCB);
        k_norms_fb<<<NPTS / 128, 256, 0, stream>>>(latent, inv_norm);
        k_c2<<<4, 256, 0, stream>>>(cbk, c2);
        k_dist_fb<<<NPTS / 128, 256, 0, stream>>>(latent, cbk, inv_norm, c2, idx, out_idx);
        k_gather<<<NPTS / 64, 256, 0, stream>>>(cbk, idx, out_q);
    }
}

// Round 5
// 234.569 us; speedup vs baseline: 2.2482x; 1.0743x over previous
//
#include <hip/hip_runtime.h>
#include <hip/hip_bf16.h>

// Problem: latent (16,192,64,64) fp32, codebook (1024,192) fp32.
// N = 65536 points, D = 192, K = 1024.
// d_out = [quantized: 12582912 fp32][indices-as-float: 65536].

#define NPTS   65536
#define DIMS   192
#define KCB    1024
#define HW     4096
#define QELEMS 12582912

typedef __attribute__((ext_vector_type(8))) _Float16 f16x8;
typedef __attribute__((ext_vector_type(4))) _Float16 f16x4;
typedef __attribute__((ext_vector_type(4))) float f32x4;

// ============================ f16 MFMA path =============================
// A = f16(raw latent), B = f16(codebook); dist = c2[k] - 2*inv_n*(A.B).
// Worst-case dist err <= 4u + flush + accum ~ 2.1e-3 (u = 2^-11).
// Quant grid 2^-20; MARGIN_Q = 4864 (4.64e-3) >= 2x bound -> narrow-gap
// points (est ~8k) get exact fp32 batched rescore.
#define MARGIN_Q 4864u

__device__ __forceinline__ void async_load16(const void* g, void* l) {
    __builtin_amdgcn_global_load_lds(
        (const __attribute__((address_space(1))) unsigned int*)g,
        (__attribute__((address_space(3))) unsigned int*)l, 16, 0, 0);
}

__device__ __forceinline__ unsigned qdist(float d) {
    float t = (d + 1.0f) * 1048576.0f;          // dist in [-1,3] -> [0,2^22)
    t = fminf(fmaxf(t, 0.0f), 4194303.0f);
    return (unsigned)t;
}

__device__ __forceinline__ void top2_merge(unsigned& b, unsigned& s,
                                           unsigned ob, unsigned os) {
    unsigned nb = min(b, ob);
    unsigned ns = min(max(b, ob), min(s, os));
    b = nb; s = ns;
}

// ---- codebook -> f16, group-major [g][k][64] (g = dims g*64..g*64+63) ----
__global__ __launch_bounds__(256) void k_prep_cb16(const float* __restrict__ cbk,
                                                   _Float16* __restrict__ Bpf) {
    int id = blockIdx.x * 256 + threadIdx.x;    // 196608
    if (id >= KCB * DIMS) return;
    int k = id / DIMS, d = id % DIMS;
    Bpf[((size_t)(d >> 6) * KCB + k) * 64 + (d & 63)] = (_Float16)cbk[id];
}

// ---- codebook row squared norms ----
__global__ __launch_bounds__(256) void k_c2(const float* __restrict__ cbk,
                                            float* __restrict__ c2) {
    int k = blockIdx.x * 256 + threadIdx.x;
    if (k >= KCB) return;
    const float4* row = (const float4*)(cbk + (size_t)k * DIMS);
    float s = 0.f;
    #pragma unroll
    for (int i = 0; i < DIMS / 4; ++i) {
        float4 v = row[i];
        s += v.x * v.x + v.y * v.y + v.z * v.z + v.w * v.w;
    }
    c2[k] = s;
}

// ---- transpose codebook fp32: cbkT[d][k] (for coalesced rescore) ----
__global__ __launch_bounds__(256) void k_cbT(const float* __restrict__ cbk,
                                             float* __restrict__ cbkT) {
    __shared__ float q[64 * 193];
    const int tid = threadIdx.x;
    const int k0 = blockIdx.x * 64;
    const int lane = tid & 63;
    const int grp = tid >> 6;
    for (int r = grp; r < 64; r += 4) {
        const float* row = cbk + (size_t)(k0 + r) * DIMS;
        for (int c = lane; c < DIMS; c += 64) q[r * 193 + c] = row[c];
    }
    __syncthreads();
    for (int d = grp; d < DIMS; d += 4) {
        cbkT[(size_t)d * KCB + k0 + lane] = q[lane * 193 + d];
    }
}

// ---- fused: latent->f16 LDS slab + MFMA GEMM + argmin + gather ----
// grid 512 (128 points each); 4 waves = 2x2 of 64x64 MFMA tiles.
// A-slab (128 x 192 f16, row pad 200 -> uniform b128 bank coverage) is
// resident in LDS; per (nb,g) only the 16 KB B-tile is staged.
__global__ __launch_bounds__(256, 2) void k_gemm_f(const float* __restrict__ latent,
                                                   const _Float16* __restrict__ Bpf,
                                                   const float* __restrict__ c2,
                                                   const float* __restrict__ cbk,
                                                   float* __restrict__ out_q,
                                                   float* __restrict__ idxf,
                                                   int* __restrict__ list,
                                                   int* __restrict__ cnt) {
    __shared__ __align__(16) _Float16 As[128 * 200];   // 51200 B
    __shared__ __align__(16) _Float16 Bs[128 * 64];    // 16384 B
    __shared__ float inv_s[128];
    __shared__ uint2 t2buf[256];
    __shared__ int sidx[128];

    const int tid = threadIdx.x;
    const int wave = tid >> 6;
    const int lane = tid & 63;
    const int quad = lane >> 4;
    const int l15 = lane & 15;
    const int wm = (wave >> 1) * 64;
    const int wn = (wave & 1) * 64;
    const int n0 = blockIdx.x * 128;
    const int bB = n0 >> 12;
    const int hw0 = n0 & 4095;

    // ---- phase 0: load raw latent slab once, f16-convert, ssq ----
    {
        float* part = (float*)Bs;               // overlay (pre-K-loop)
        const float* lat = latent + (size_t)bB * DIMS * HW + hw0;
        const int p = tid & 127, ch = tid >> 7;
        float ss = 0.f;
        #pragma unroll 4
        for (int i = 0; i < 24; ++i) {
            int c0 = i * 8 + ch * 4;
            float v0 = lat[(size_t)(c0 + 0) * HW + p];
            float v1 = lat[(size_t)(c0 + 1) * HW + p];
            float v2 = lat[(size_t)(c0 + 2) * HW + p];
            float v3 = lat[(size_t)(c0 + 3) * HW + p];
            ss = fmaf(v0, v0, fmaf(v1, v1, fmaf(v2, v2, fmaf(v3, v3, ss))));
            f16x4 h = { (_Float16)v0, (_Float16)v1, (_Float16)v2, (_Float16)v3 };
            *(f16x4*)&As[p * 200 + c0] = h;
        }
        part[ch * 128 + p] = ss;
        __syncthreads();
        if (tid < 128)
            inv_s[tid] = 1.0f / (sqrtf(part[tid] + part[128 + tid]) + 1e-8f);
        __syncthreads();                        // part consumed before Bs reuse
    }

    unsigned rb[16], rs[16];
    #pragma unroll
    for (int i = 0; i < 16; ++i) { rb[i] = 0xFFFFFFFFu; rs[i] = 0xFFFFFFFFu; }

    // ---- K-loop: nb (8 codeword strips) x g (3 dim groups) ----
    for (int nb = 0; nb < 8; ++nb) {
        f32x4 acc[4][4];
        #pragma unroll
        for (int mt = 0; mt < 4; ++mt)
            #pragma unroll
            for (int nt = 0; nt < 4; ++nt)
                #pragma unroll
                for (int r = 0; r < 4; ++r) acc[mt][nt][r] = 0.f;

        for (int g = 0; g < 3; ++g) {
            __syncthreads();
            #pragma unroll
            for (int i = 0; i < 4; ++i) {
                int u = i * 256 + tid;          // 1024 16B-units
                int m = u >> 3, c = u & 7;
                int sw = c ^ (m & 7);           // XOR swizzle
                async_load16(Bpf + (((size_t)g * KCB + nb * 128 + m) * 8 + sw) * 8,
                             &Bs[u * 8]);
            }
            __syncthreads();
            #pragma unroll
            for (int s = 0; s < 2; ++s) {
                f16x8 af[4], bfr[4];
                #pragma unroll
                for (int mt = 0; mt < 4; ++mt) {
                    int m = wm + mt * 16 + l15;
                    af[mt] = *(const f16x8*)&As[m * 200 + g * 64 + s * 32 + quad * 8];
                }
                #pragma unroll
                for (int nt = 0; nt < 4; ++nt) {
                    int n = wn + nt * 16 + l15;
                    int c = (s * 4 + quad) ^ (n & 7);
                    bfr[nt] = *(const f16x8*)&Bs[n * 64 + c * 8];
                }
                #pragma unroll
                for (int mt = 0; mt < 4; ++mt)
                    #pragma unroll
                    for (int nt = 0; nt < 4; ++nt)
                        acc[mt][nt] = __builtin_amdgcn_mfma_f32_16x16x32_f16(
                            af[mt], bfr[nt], acc[mt][nt], 0, 0, 0);
            }
        }

        // per-nb epilogue: dist = c2 - 2*inv*dot; merge into running top-2
        int kbase = nb * 128 + wn;
        float c2v[4];
        #pragma unroll
        for (int nt = 0; nt < 4; ++nt) c2v[nt] = c2[kbase + nt * 16 + l15];
        #pragma unroll
        for (int mt = 0; mt < 4; ++mt) {
            #pragma unroll
            for (int r = 0; r < 4; ++r) {
                float inv = inv_s[wm + mt * 16 + quad * 4 + r];
                unsigned p[4];
                #pragma unroll
                for (int nt = 0; nt < 4; ++nt) {
                    float dist = fmaf(-2.f * inv, acc[mt][nt][r], c2v[nt]);
                    p[nt] = (qdist(dist) << 10) | (unsigned)(kbase + nt * 16 + l15);
                }
                unsigned b01 = min(p[0], p[1]), s01 = max(p[0], p[1]);
                unsigned b23 = min(p[2], p[3]), s23 = max(p[2], p[3]);
                unsigned nbb = min(b01, b23);
                unsigned nbs = min(max(b01, b23), min(s01, s23));
                top2_merge(rb[mt * 4 + r], rs[mt * 4 + r], nbb, nbs);
            }
        }
    }

    // ---- cross-lane / cross-wave top-2 merge ----
    __syncthreads();
    #pragma unroll
    for (int i = 0; i < 16; ++i) {
        unsigned b = rb[i], s = rs[i];
        #pragma unroll
        for (int off = 1; off < 16; off <<= 1) {
            unsigned ob = __shfl_xor(b, off, 64);
            unsigned os = __shfl_xor(s, off, 64);
            top2_merge(b, s, ob, os);
        }
        if (l15 == 0) {
            int mt = i >> 2, r = i & 3;
            int mloc = wm + mt * 16 + quad * 4 + r;
            t2buf[mloc * 2 + (wave & 1)] = make_uint2(b, s);
        }
    }
    __syncthreads();
    if (tid < 128) {
        uint2 x = t2buf[tid * 2];
        uint2 y = t2buf[tid * 2 + 1];
        unsigned b = x.x, s = x.y;
        top2_merge(b, s, y.x, y.y);
        int k = (int)(b & 1023u);
        sidx[tid] = k;
        idxf[n0 + tid] = (float)k;
        if (((s >> 10) - (b >> 10)) < MARGIN_Q) {
            int pos = atomicAdd(cnt, 1);
            list[pos] = n0 + tid;
        }
    }
    __syncthreads();

    // ---- gather epilogue (q overlays As) ----
    float* q = (float*)As;                      // 32*193*4 = 24.7 KB
    for (int chk = 0; chk < 4; ++chk) {
        int p0 = chk * 32;
        for (int r = wave; r < 32; r += 4) {
            const float* row = cbk + (size_t)sidx[p0 + r] * DIMS;
            for (int c = lane; c < DIMS; c += 64) q[r * 193 + c] = row[c];
        }
        __syncthreads();
        float* ob = out_q + (size_t)bB * DIMS * HW + hw0 + p0;
        #pragma unroll
        for (int i = 0; i < 24; ++i) {
            int u = i * 256 + tid;
            int c = u >> 5, p = u & 31;
            ob[(size_t)c * HW + p] = q[p * 193 + c];
        }
        __syncthreads();
    }
}

// ---- batched exact fp32 rescore: 16 flagged points per block ----
__global__ __launch_bounds__(256) void k_rescore16(const float* __restrict__ latent,
                                                   const float* __restrict__ cbkT,
                                                   const float* __restrict__ cbk,
                                                   const float* __restrict__ c2,
                                                   const int* __restrict__ list,
                                                   const int* __restrict__ cnt,
                                                   float* __restrict__ out_q,
                                                   float* __restrict__ idxf) {
    __shared__ float xs[16][200];
    __shared__ float part[16][16];
    __shared__ float inv_s[16];
    __shared__ unsigned long long best[16];
    const int tid = threadIdx.x;
    const int count = *cnt;
    const float4* ct = (const float4*)cbkT;     // [d][256] float4
    const int j = tid >> 4, dl = tid & 15;

    for (int base = blockIdx.x * 16; base < count; base += gridDim.x * 16) {
        __syncthreads();                        // guard xs/best reuse
        float ss = 0.f;
        int n = 0, bb = 0, hw = 0;
        bool valid = (base + j) < count;
        if (valid) {
            n = list[base + j]; bb = n >> 12; hw = n & 4095;
            #pragma unroll
            for (int i = 0; i < 12; ++i) {
                int d = dl + i * 16;
                float v = latent[((size_t)bb * DIMS + d) * HW + hw];
                xs[j][d] = v;
                ss = fmaf(v, v, ss);
            }
        }
        part[j][dl] = ss;
        if (tid < 16) best[tid] = ~0ull;
        __syncthreads();
        if (tid < 16) {
            float s = 0.f;
            #pragma unroll
            for (int i = 0; i < 16; ++i) s += part[tid][i];
            inv_s[tid] = 1.0f / (sqrtf(s) + 1e-8f);
        }
        __syncthreads();

        // dots: thread owns codewords 4*tid..4*tid+3 for all 16 points
        float4 a[16];
        #pragma unroll
        for (int p = 0; p < 16; ++p) a[p] = make_float4(0.f, 0.f, 0.f, 0.f);
        for (int d = 0; d < DIMS; d += 4) {
            float4 cv0 = ct[(size_t)(d + 0) * 256 + tid];
            float4 cv1 = ct[(size_t)(d + 1) * 256 + tid];
            float4 cv2 = ct[(size_t)(d + 2) * 256 + tid];
            float4 cv3 = ct[(size_t)(d + 3) * 256 + tid];
            #pragma unroll
            for (int p = 0; p < 16; ++p) {
                float4 xv = *(const float4*)&xs[p][d];
                a[p].x = fmaf(xv.x, cv0.x, a[p].x); a[p].y = fmaf(xv.x, cv0.y, a[p].y);
                a[p].z = fmaf(xv.x, cv0.z, a[p].z); a[p].w = fmaf(xv.x, cv0.w, a[p].w);
                a[p].x = fmaf(xv.y, cv1.x, a[p].x); a[p].y = fmaf(xv.y, cv1.y, a[p].y);
                a[p].z = fmaf(xv.y, cv1.z, a[p].z); a[p].w = fmaf(xv.y, cv1.w, a[p].w);
                a[p].x = fmaf(xv.z, cv2.x, a[p].x); a[p].y = fmaf(xv.z, cv2.y, a[p].y);
                a[p].z = fmaf(xv.z, cv2.z, a[p].z); a[p].w = fmaf(xv.z, cv2.w, a[p].w);
                a[p].x = fmaf(xv.w, cv3.x, a[p].x); a[p].y = fmaf(xv.w, cv3.y, a[p].y);
                a[p].z = fmaf(xv.w, cv3.z, a[p].z); a[p].w = fmaf(xv.w, cv3.w, a[p].w);
            }
        }
        #pragma unroll
        for (int p = 0; p < 16; ++p) {
            float inv = inv_s[p];
            float dot4[4] = {a[p].x, a[p].y, a[p].z, a[p].w};
            unsigned long long loc = ~0ull;
            #pragma unroll
            for (int e = 0; e < 4; ++e) {
                int k = 4 * tid + e;
                float dist = c2[k] - 2.f * inv * dot4[e];
                unsigned ub = __float_as_uint(dist);
                ub ^= (ub >> 31) ? 0xFFFFFFFFu : 0x80000000u;   // monotonic
                unsigned long long pk =
                    ((unsigned long long)ub << 32) | (unsigned)k;
                loc = loc < pk ? loc : pk;
            }
            #pragma unroll
            for (int off = 1; off < 64; off <<= 1) {
                unsigned long long o = __shfl_xor(loc, off, 64);
                loc = loc < o ? loc : o;
            }
            if ((tid & 63) == 0) atomicMin(&best[p], loc);
        }
        __syncthreads();
        if (valid) {
            int kk = (int)(best[j] & 0xFFFFFFFFull);
            #pragma unroll
            for (int i = 0; i < 12; ++i) {
                int d = dl + i * 16;
                out_q[((size_t)bb * DIMS + d) * HW + hw] = cbk[(size_t)kk * DIMS + d];
            }
            if (dl == 0) idxf[n] = (float)kk;
        }
    }
}

// ======================= fallback fp32 path (round-1) ====================
__global__ __launch_bounds__(256) void k_norms_fb(const float* __restrict__ latent,
                                                  float* __restrict__ inv_norm) {
    __shared__ float red[256];
    const int tid = threadIdx.x;
    const int n0 = blockIdx.x * 128;
    const int nl = tid & 127;
    const int half = tid >> 7;
    const int b = n0 >> 12;
    const int hw = (n0 & 4095) + nl;
    const float* base = latent + (size_t)b * DIMS * HW + hw;
    float ssq = 0.f;
    for (int c = half; c < DIMS; c += 2) {
        float v = base[(size_t)c * HW];
        ssq = fmaf(v, v, ssq);
    }
    red[tid] = ssq;
    __syncthreads();
    if (half == 0) {
        float s = red[tid] + red[tid + 128];
        inv_norm[n0 + nl] = 1.0f / (sqrtf(s) + 1e-8f);
    }
}

#define LDX  132
__global__ __launch_bounds__(256) void k_dist_fb(const float* __restrict__ latent,
                                                 const float* __restrict__ cbk,
                                                 const float* __restrict__ inv_norm,
                                                 const float* __restrict__ c2,
                                                 int* __restrict__ idx_out,
                                                 float* __restrict__ idxf_out) {
    __shared__ __align__(16) float xsm[64 * LDX];
    __shared__ __align__(16) float csm[64 * LDX];
    __shared__ unsigned long long red[128];
    const int tid = threadIdx.x;
    const int n0 = blockIdx.x * 128;
    const int b = n0 >> 12;
    const int hw0 = n0 & 4095;
    const int kt = tid & 15;
    const int mt = tid >> 4;
    const float* lat_base = latent + (size_t)b * DIMS * HW + hw0;
    float inv[8];
    #pragma unroll
    for (int i = 0; i < 8; ++i) inv[i] = inv_norm[n0 + mt * 8 + i];
    float best[8];
    int bidx[8];
    #pragma unroll
    for (int i = 0; i < 8; ++i) { best[i] = 3.4e38f; bidx[i] = 0; }
    const int nl = tid & 127;
    const int cp = tid >> 7;
    for (int k0 = 0; k0 < KCB; k0 += 128) {
        float acc[8][8];
        #pragma unroll
        for (int i = 0; i < 8; ++i)
            #pragma unroll
            for (int j = 0; j < 8; ++j) acc[i][j] = 0.f;
        for (int d0 = 0; d0 < DIMS; d0 += 64) {
            __syncthreads();
            for (int cc = cp; cc < 64; cc += 2)
                xsm[cc * LDX + nl] = lat_base[(size_t)(d0 + cc) * HW + nl];
            #pragma unroll
            for (int i = 0; i < 8; ++i) {
                int f4 = tid + 256 * i;
                int kk = f4 >> 4;
                int dq = f4 & 15;
                float4 v = *(const float4*)(cbk + (size_t)(k0 + kk) * DIMS + d0 + dq * 4);
                csm[(dq * 4 + 0) * LDX + kk] = v.x;
                csm[(dq * 4 + 1) * LDX + kk] = v.y;
                csm[(dq * 4 + 2) * LDX + kk] = v.z;
                csm[(dq * 4 + 3) * LDX + kk] = v.w;
            }
            __syncthreads();
            for (int d = 0; d < 64; ++d) {
                const float* xr = &xsm[d * LDX + mt * 8];
                const float* cr = &csm[d * LDX + kt * 8];
                float x8[8], c8[8];
                *(float4*)&x8[0] = *(const float4*)&xr[0];
                *(float4*)&x8[4] = *(const float4*)&xr[4];
                *(float4*)&c8[0] = *(const float4*)&cr[0];
                *(float4*)&c8[4] = *(const float4*)&cr[4];
                #pragma unroll
                for (int i = 0; i < 8; ++i)
                    #pragma unroll
                    for (int j = 0; j < 8; ++j)
                        acc[i][j] = fmaf(x8[i], c8[j], acc[i][j]);
            }
        }
        float cc2[8];
        #pragma unroll
        for (int j = 0; j < 8; ++j) cc2[j] = c2[k0 + kt * 8 + j];
        #pragma unroll
        for (int i = 0; i < 8; ++i)
            #pragma unroll
            for (int j = 0; j < 8; ++j) {
                float t = inv[i] * acc[i][j];
                float dist = fmaf(-2.f, t, cc2[j]);
                int kidx = k0 + kt * 8 + j;
                if (dist < best[i]) { best[i] = dist; bidx[i] = kidx; }
            }
    }
    if (tid < 128) red[tid] = ~0ull;
    __syncthreads();
    #pragma unroll
    for (int i = 0; i < 8; ++i) {
        unsigned long long p =
            ((unsigned long long)__float_as_uint(best[i]) << 32) | (unsigned)bidx[i];
        atomicMin(&red[mt * 8 + i], p);
    }
    __syncthreads();
    if (tid < 128) {
        int k = (int)(red[tid] & 0xFFFFFFFFu);
        idx_out[n0 + tid] = k;
        idxf_out[n0 + tid] = (float)k;
    }
}

__global__ __launch_bounds__(256) void k_gather(const float* __restrict__ cbk,
                                                const int* __restrict__ idx,
                                                float* __restrict__ out) {
    __shared__ float q[64 * 193];
    __shared__ int sidx[64];
    const int tid = threadIdx.x;
    const int n0 = blockIdx.x * 64;
    const int b = n0 >> 12;
    const int hw0 = n0 & 4095;
    const int lane = tid & 63;
    const int grp = tid >> 6;

    if (tid < 64) sidx[tid] = idx[n0 + tid];
    __syncthreads();
    for (int r = grp; r < 64; r += 4) {
        const float* row = cbk + (size_t)sidx[r] * DIMS;
        for (int c = lane; c < DIMS; c += 64) q[r * 193 + c] = row[c];
    }
    __syncthreads();
    float* obase = out + (size_t)b * DIMS * HW + hw0;
    for (int c = grp; c < DIMS; c += 4) {
        obase[(size_t)c * HW + lane] = q[lane * 193 + c];
    }
}

// ================================ launch ================================
extern "C" void kernel_launch(void* const* d_in, const int* in_sizes, int n_in,
                              void* d_out, int out_size, void* d_ws, size_t ws_size,
                              hipStream_t stream) {
    const float* latent = (const float*)d_in[0];
    const float* cbk = (const float*)d_in[1];
    float* out = (float*)d_out;
    float* out_q = out;
    float* out_idx = out + QELEMS;

    if (ws_size >= 2u * 1024u * 1024u) {
        // ws layout (bytes):
        char* w = (char*)d_ws;
        _Float16* Bpf = (_Float16*)w;                          //    393,216
        float* cbkT = (float*)(w + 393216);                    //    786,432
        float* c2 = (float*)(w + 1179648);                     //      4,096
        int* list = (int*)(w + 1183744);                       //    262,144
        int* cnt = (int*)(w + 1445888);                        //          4

        hipMemsetAsync(cnt, 0, 4, stream);
        k_prep_cb16<<<768, 256, 0, stream>>>(cbk, Bpf);
        k_c2<<<4, 256, 0, stream>>>(cbk, c2);
        k_cbT<<<KCB / 64, 256, 0, stream>>>(cbk, cbkT);
        k_gemm_f<<<512, 256, 0, stream>>>(latent, Bpf, c2, cbk, out_q, out_idx,
                                          list, cnt);
        k_rescore16<<<512, 256, 0, stream>>>(latent, cbkT, cbk, c2, list, cnt,
                                             out_q, out_idx);
    } else {
        float* inv_norm = (float*)d_ws;
        float* c2 = inv_norm + NPTS;
        int* idx = (int*)(c2 + KCB);
        k_norms_fb<<<NPTS / 128, 256, 0, stream>>>(latent, inv_norm);
        k_c2<<<4, 256, 0, stream>>>(cbk, c2);
        k_dist_fb<<<NPTS / 128, 256, 0, stream>>>(latent, cbk, inv_norm, c2, idx, out_idx);
        k_gather<<<NPTS / 64, 256, 0, stream>>>(cbk, idx, out_q);
    }
}